// Round 1
// baseline (1105.625 us; speedup 1.0000x reference)
//
#include <hip/hip_runtime.h>
#include <hip/hip_bf16.h>
#include <stdint.h>

// MoE: T=8192 tokens, D=1024, H=4096, E=16 experts, top-2.
// Sparse dispatch: only 2 experts per token are computed (reference multiplies
// the rest by zero). bf16 MFMA GEMMs, fp32 accumulate.

#define Tn 8192
#define Dn 1024
#define Hn 4096
#define En 16

typedef __attribute__((ext_vector_type(8))) short bf16x8;
typedef __attribute__((ext_vector_type(4))) float f32x4;

__device__ __forceinline__ unsigned short f2bf(float f) {
    union { __hip_bfloat16 h; unsigned short u; } cv;
    cv.h = __float2bfloat16(f);
    return cv.u;
}

// async global->LDS, 16B per lane. LDS dest must be wave-uniform base + lane*16.
__device__ __forceinline__ void gload_lds16(const void* gptr, void* lptr) {
    __builtin_amdgcn_global_load_lds(
        (const __attribute__((address_space(1))) uint32_t*)gptr,
        (__attribute__((address_space(3))) uint32_t*)lptr, 16, 0, 0);
}

// ---------------- gate: logits -> top2 -> softmax -> slot assignment --------
__global__ __launch_bounds__(256) void gate_kernel(
    const float* __restrict__ x, const float* __restrict__ Wg,
    const float* __restrict__ bg,
    int* cnt, int* tok_e, int* tok_pos, float* tok_w)
{
    int t = blockIdx.x;
    int tid = threadIdx.x;
    __shared__ float part[256][17];   // +1 pad -> conflict-free strided access
    __shared__ float logits[16];

    float p[16];
#pragma unroll
    for (int e = 0; e < 16; e++) p[e] = 0.f;

    float4 xv = *reinterpret_cast<const float4*>(x + (size_t)t * Dn + tid * 4);
    float xs[4] = {xv.x, xv.y, xv.z, xv.w};
#pragma unroll
    for (int j = 0; j < 4; j++) {
        int row = tid * 4 + j;
        const float4* wrow = reinterpret_cast<const float4*>(Wg + (size_t)row * 16);
#pragma unroll
        for (int q = 0; q < 4; q++) {
            float4 w4 = wrow[q];
            p[q * 4 + 0] += xs[j] * w4.x;
            p[q * 4 + 1] += xs[j] * w4.y;
            p[q * 4 + 2] += xs[j] * w4.z;
            p[q * 4 + 3] += xs[j] * w4.w;
        }
    }
#pragma unroll
    for (int e = 0; e < 16; e++) part[tid][e] = p[e];
    __syncthreads();
    // deterministic tree reduction (fixed order -> bitwise stable routing)
    for (int off = 128; off > 0; off >>= 1) {
        if (tid < off) {
#pragma unroll
            for (int e = 0; e < 16; e++) part[tid][e] += part[tid + off][e];
        }
        __syncthreads();
    }
    if (tid < 16) logits[tid] = part[0][tid] + bg[tid];
    __syncthreads();
    if (tid == 0) {
        float v0 = -1e30f, v1 = -1e30f; int i0 = -1, i1 = -1;
        for (int e = 0; e < 16; e++) { float v = logits[e]; if (v > v0) { v0 = v; i0 = e; } }
        for (int e = 0; e < 16; e++) { if (e == i0) continue; float v = logits[e]; if (v > v1) { v1 = v; i1 = e; } }
        float ex = __expf(v1 - v0);
        float w0 = 1.f / (1.f + ex);
        float w1 = ex / (1.f + ex);
        int p0 = atomicAdd(&cnt[i0], 1);
        int p1 = atomicAdd(&cnt[i1], 1);
        tok_e[t * 2 + 0] = i0; tok_e[t * 2 + 1] = i1;
        tok_pos[t * 2 + 0] = p0; tok_pos[t * 2 + 1] = p1;
        tok_w[t * 2 + 0] = w0; tok_w[t * 2 + 1] = w1;
    }
}

// ---------------- scan: row bases + tile bases ------------------------------
__global__ void scan_kernel(const int* cnt, int* base, int* tb1, int* tb2)
{
    if (threadIdx.x == 0 && blockIdx.x == 0) {
        int b = 0, a1 = 0, a2 = 0;
        for (int e = 0; e < En; e++) {
            base[e] = b; tb1[e] = a1; tb2[e] = a2;
            int c = cnt[e];
            int mt = (c + 127) >> 7;
            b += c; a1 += mt * (Hn / 128); a2 += mt * (Dn / 128);
        }
        base[En] = b; tb1[En] = a1; tb2[En] = a2;
    }
}

// ---------------- gather: x -> xg (bf16, expert-contiguous rows) ------------
__global__ __launch_bounds__(256) void gather_kernel(
    const float* __restrict__ x, const int* tok_e, const int* tok_pos,
    const float* tok_w, const int* base,
    unsigned short* xg, int* rowtok, float* roww)
{
    int t = blockIdx.x; int tid = threadIdx.x;
    int e0 = tok_e[2 * t], e1 = tok_e[2 * t + 1];
    int r0 = base[e0] + tok_pos[2 * t];
    int r1 = base[e1] + tok_pos[2 * t + 1];
    float4 v = *reinterpret_cast<const float4*>(x + (size_t)t * Dn + tid * 4);
    ushort4 u;
    u.x = f2bf(v.x); u.y = f2bf(v.y); u.z = f2bf(v.z); u.w = f2bf(v.w);
    *reinterpret_cast<ushort4*>(xg + (size_t)r0 * Dn + tid * 4) = u;
    *reinterpret_cast<ushort4*>(xg + (size_t)r1 * Dn + tid * 4) = u;
    if (tid == 0) {
        rowtok[r0] = t; roww[r0] = tok_w[2 * t];
        rowtok[r1] = t; roww[r1] = tok_w[2 * t + 1];
    }
}

// ---------------- convert + transpose weights: [R][C] f32 -> [C][R] bf16 ----
__global__ __launch_bounds__(256) void convT_kernel(
    const float* __restrict__ src, unsigned short* __restrict__ dst, int R, int C)
{
    int e = blockIdx.z;
    const float* s = src + (size_t)e * R * C;
    unsigned short* d = dst + (size_t)e * R * C;
    __shared__ float tile[32][33];
    int r0 = blockIdx.y * 32, c0 = blockIdx.x * 32;
    int tr = threadIdx.x >> 3;          // 0..31
    int tc4 = (threadIdx.x & 7) * 4;    // 0..28
    float4 v = *reinterpret_cast<const float4*>(s + (size_t)(r0 + tr) * C + c0 + tc4);
    tile[tr][tc4 + 0] = v.x; tile[tr][tc4 + 1] = v.y;
    tile[tr][tc4 + 2] = v.z; tile[tr][tc4 + 3] = v.w;
    __syncthreads();
    int oc = tr;          // dst row within tile (a source column)
    int or4 = tc4;        // dst col (a source row), 4-wide
    ushort4 u;
    u.x = f2bf(tile[or4 + 0][oc]);
    u.y = f2bf(tile[or4 + 1][oc]);
    u.z = f2bf(tile[or4 + 2][oc]);
    u.w = f2bf(tile[or4 + 3][oc]);
    *reinterpret_cast<ushort4*>(d + (size_t)(c0 + oc) * R + r0 + or4) = u;
}

// ---------------- GEMM1: hg = relu(xg @ W1 + b1), bf16 out ------------------
// A: xg rows [base[e]+m0 ..], lda=Dn. B^T: w1t [E][Hn][Dn]. 128x128 tile, BK=32.
__global__ __launch_bounds__(256) void gemm1_kernel(
    const unsigned short* __restrict__ xg, const unsigned short* __restrict__ w1t,
    const float* __restrict__ b1, unsigned short* __restrict__ hg,
    const int* cnt, const int* base, const int* tb)
{
    __shared__ unsigned short ldsA[128 * 32];
    __shared__ unsigned short ldsB[128 * 32];
    int tid = threadIdx.x;
    int total = tb[En];
    for (int tile = blockIdx.x; tile < total; tile += gridDim.x) {
        int e = 0;
        while (tb[e + 1] <= tile) e++;
        int local = tile - tb[e];
        int mtile = local >> 5;          // Hn/128 = 32 n-tiles
        int ntile = local & 31;
        int M_e = cnt[e];
        int m0 = mtile * 128, n0 = ntile * 128;
        int rowbase0 = base[e] + m0;
        const unsigned short* Ab = xg + (size_t)rowbase0 * Dn;
        const unsigned short* Bb = w1t + (size_t)e * Hn * Dn + (size_t)n0 * Dn;

        f32x4 acc[4][4];
#pragma unroll
        for (int m = 0; m < 4; m++)
#pragma unroll
            for (int n = 0; n < 4; n++) acc[m][n] = (f32x4){0.f, 0.f, 0.f, 0.f};

        int lane = tid & 63, wid = tid >> 6;
        int wm = (wid >> 1) * 64, wn = (wid & 1) * 64;
        int lr16 = lane & 15, lk = lane >> 4;

        for (int k0 = 0; k0 < Dn; k0 += 32) {
            __syncthreads();
#pragma unroll
            for (int i = 0; i < 2; i++) {
                int c = tid + i * 256;
                int row = c >> 2, col = c & 3;
                gload_lds16(Ab + (size_t)row * Dn + k0 + col * 8, (char*)ldsA + c * 16);
                gload_lds16(Bb + (size_t)row * Dn + k0 + col * 8, (char*)ldsB + c * 16);
            }
            __syncthreads();
            bf16x8 a[4], b[4];
#pragma unroll
            for (int m = 0; m < 4; m++)
                a[m] = *(const bf16x8*)(ldsA + (wm + m * 16 + lr16) * 32 + lk * 8);
#pragma unroll
            for (int n = 0; n < 4; n++)
                b[n] = *(const bf16x8*)(ldsB + (wn + n * 16 + lr16) * 32 + lk * 8);
#pragma unroll
            for (int m = 0; m < 4; m++)
#pragma unroll
                for (int n = 0; n < 4; n++)
                    acc[m][n] = __builtin_amdgcn_mfma_f32_16x16x32_bf16(a[m], b[n], acc[m][n], 0, 0, 0);
        }
        __syncthreads();
        // epilogue: C/D map col=lane&15, row=(lane>>4)*4+j
        const float* b1e = b1 + (size_t)e * Hn;
        int lj = (lane >> 4) * 4;
#pragma unroll
        for (int n = 0; n < 4; n++) {
            int col = n0 + wn + n * 16 + lr16;
            float bias = b1e[col];
#pragma unroll
            for (int m = 0; m < 4; m++) {
#pragma unroll
                for (int j = 0; j < 4; j++) {
                    int rl = wm + m * 16 + lj + j;
                    if (m0 + rl < M_e) {
                        float v = fmaxf(acc[m][n][j] + bias, 0.f);
                        hg[(size_t)(rowbase0 + rl) * Hn + col] = f2bf(v);
                    }
                }
            }
        }
    }
}

// ---------------- GEMM2: out[tok] += w * (hg @ W2 + b2) ---------------------
// A: hg rows, lda=Hn. B^T: w2t [E][Dn][Hn]. Scatter via atomicAdd (2 commutative
// adds per output element -> deterministic).
__global__ __launch_bounds__(256) void gemm2_kernel(
    const unsigned short* __restrict__ hg, const unsigned short* __restrict__ w2t,
    const float* __restrict__ b2, float* __restrict__ out,
    const int* cnt, const int* base, const int* tb,
    const int* rowtok, const float* roww)
{
    __shared__ unsigned short ldsA[128 * 32];
    __shared__ unsigned short ldsB[128 * 32];
    int tid = threadIdx.x;
    int total = tb[En];
    for (int tile = blockIdx.x; tile < total; tile += gridDim.x) {
        int e = 0;
        while (tb[e + 1] <= tile) e++;
        int local = tile - tb[e];
        int mtile = local >> 3;          // Dn/128 = 8 n-tiles
        int ntile = local & 7;
        int M_e = cnt[e];
        int m0 = mtile * 128, n0 = ntile * 128;
        int rowbase0 = base[e] + m0;
        const unsigned short* Ab = hg + (size_t)rowbase0 * Hn;
        const unsigned short* Bb = w2t + (size_t)e * Dn * Hn + (size_t)n0 * Hn;

        f32x4 acc[4][4];
#pragma unroll
        for (int m = 0; m < 4; m++)
#pragma unroll
            for (int n = 0; n < 4; n++) acc[m][n] = (f32x4){0.f, 0.f, 0.f, 0.f};

        int lane = tid & 63, wid = tid >> 6;
        int wm = (wid >> 1) * 64, wn = (wid & 1) * 64;
        int lr16 = lane & 15, lk = lane >> 4;

        for (int k0 = 0; k0 < Hn; k0 += 32) {
            __syncthreads();
#pragma unroll
            for (int i = 0; i < 2; i++) {
                int c = tid + i * 256;
                int row = c >> 2, col = c & 3;
                gload_lds16(Ab + (size_t)row * Hn + k0 + col * 8, (char*)ldsA + c * 16);
                gload_lds16(Bb + (size_t)row * Hn + k0 + col * 8, (char*)ldsB + c * 16);
            }
            __syncthreads();
            bf16x8 a[4], b[4];
#pragma unroll
            for (int m = 0; m < 4; m++)
                a[m] = *(const bf16x8*)(ldsA + (wm + m * 16 + lr16) * 32 + lk * 8);
#pragma unroll
            for (int n = 0; n < 4; n++)
                b[n] = *(const bf16x8*)(ldsB + (wn + n * 16 + lr16) * 32 + lk * 8);
#pragma unroll
            for (int m = 0; m < 4; m++)
#pragma unroll
                for (int n = 0; n < 4; n++)
                    acc[m][n] = __builtin_amdgcn_mfma_f32_16x16x32_bf16(a[m], b[n], acc[m][n], 0, 0, 0);
        }
        __syncthreads();
        const float* b2e = b2 + (size_t)e * Dn;
        int lj = (lane >> 4) * 4;
#pragma unroll
        for (int m = 0; m < 4; m++) {
            int rt_[4]; float rw_[4]; bool valid[4];
#pragma unroll
            for (int j = 0; j < 4; j++) {
                int rl = wm + m * 16 + lj + j;
                valid[j] = (m0 + rl < M_e);
                int rowg = rowbase0 + rl;
                rt_[j] = valid[j] ? rowtok[rowg] : 0;
                rw_[j] = valid[j] ? roww[rowg] : 0.f;
            }
#pragma unroll
            for (int n = 0; n < 4; n++) {
                int col = n0 + wn + n * 16 + lr16;
                float bias = b2e[col];
#pragma unroll
                for (int j = 0; j < 4; j++) {
                    if (valid[j]) {
                        atomicAdd(&out[(size_t)rt_[j] * Dn + col], rw_[j] * (acc[m][n][j] + bias));
                    }
                }
            }
        }
    }
}

// ---------------- launch ----------------------------------------------------
extern "C" void kernel_launch(void* const* d_in, const int* in_sizes, int n_in,
                              void* d_out, int out_size, void* d_ws, size_t ws_size,
                              hipStream_t stream)
{
    const float* x  = (const float*)d_in[0];
    const float* Wg = (const float*)d_in[1];
    const float* bg = (const float*)d_in[2];
    const float* W1 = (const float*)d_in[3];
    const float* b1 = (const float*)d_in[4];
    const float* W2 = (const float*)d_in[5];
    const float* b2 = (const float*)d_in[6];
    float* out = (float*)d_out;

    char* ws = (char*)d_ws;
    size_t off = 0;
    auto alloc = [&](size_t bytes) {
        size_t o = off; off += (bytes + 255) & ~(size_t)255; return o;
    };
    const int ROWS = Tn * 2;            // 16384 dispatch rows
    const int RCAP = ROWS + 128;        // slack for padded tile reads/writes

    unsigned short* Wt = (unsigned short*)(ws + alloc((size_t)En * Hn * Dn * 2)); // reused W1t then W2t
    unsigned short* xg = (unsigned short*)(ws + alloc((size_t)RCAP * Dn * 2));
    unsigned short* hg = (unsigned short*)(ws + alloc((size_t)RCAP * Hn * 2));
    int*   cnt     = (int*)(ws + alloc(En * 4));
    int*   base    = (int*)(ws + alloc((En + 1) * 4));
    int*   tb1     = (int*)(ws + alloc((En + 1) * 4));
    int*   tb2     = (int*)(ws + alloc((En + 1) * 4));
    int*   tok_e   = (int*)(ws + alloc(Tn * 2 * 4));
    int*   tok_pos = (int*)(ws + alloc(Tn * 2 * 4));
    float* tok_w   = (float*)(ws + alloc(Tn * 2 * 4));
    int*   rowtok  = (int*)(ws + alloc(RCAP * 4));
    float* roww    = (float*)(ws + alloc(RCAP * 4));
    (void)ws_size; (void)in_sizes; (void)n_in; (void)out_size;

    hipMemsetAsync(cnt, 0, En * 4, stream);
    hipMemsetAsync(out, 0, (size_t)Tn * Dn * 4, stream);

    gate_kernel<<<Tn, 256, 0, stream>>>(x, Wg, bg, cnt, tok_e, tok_pos, tok_w);
    scan_kernel<<<1, 64, 0, stream>>>(cnt, base, tb1, tb2);
    gather_kernel<<<Tn, 256, 0, stream>>>(x, tok_e, tok_pos, tok_w, base, xg, rowtok, roww);

    // W1 [E][Dn][Hn] -> Wt [E][Hn][Dn] bf16
    convT_kernel<<<dim3(Hn / 32, Dn / 32, En), 256, 0, stream>>>(W1, Wt, Dn, Hn);
    gemm1_kernel<<<4096, 256, 0, stream>>>(xg, Wt, b1, hg, cnt, base, tb1);

    // W2 [E][Hn][Dn] -> Wt [E][Dn][Hn] bf16 (Wt reused; stream-ordered)
    convT_kernel<<<dim3(Dn / 32, Hn / 32, En), 256, 0, stream>>>(W2, Wt, Hn, Dn);
    gemm2_kernel<<<2048, 256, 0, stream>>>(hg, Wt, b2, out, cnt, base, tb2, rowtok, roww);
}

// Round 2
// 1062.873 us; speedup vs baseline: 1.0402x; 1.0402x over previous
//
#include <hip/hip_runtime.h>
#include <hip/hip_bf16.h>
#include <stdint.h>

// MoE: T=8192 tokens, D=1024, H=4096, E=16 experts, top-2.
// Sparse dispatch: only 2 experts per token are computed. bf16 MFMA GEMMs,
// fp32 accumulate. GEMM2 writes per-row y; a combine pass does the weighted sum
// (no atomics anywhere in the hot path).

#define Tn 8192
#define Dn 1024
#define Hn 4096
#define En 16

typedef __attribute__((ext_vector_type(8))) short bf16x8;
typedef __attribute__((ext_vector_type(4))) float f32x4;

__device__ __forceinline__ unsigned short f2bf(float f) {
    union { __hip_bfloat16 h; unsigned short u; } cv;
    cv.h = __float2bfloat16(f);
    return cv.u;
}

// async global->LDS, 16B per lane. LDS dest must be wave-uniform base + lane*16.
__device__ __forceinline__ void gload_lds16(const void* gptr, void* lptr) {
    __builtin_amdgcn_global_load_lds(
        (const __attribute__((address_space(1))) uint32_t*)gptr,
        (__attribute__((address_space(3))) uint32_t*)lptr, 16, 0, 0);
}

// bijective XCD-chunked swizzle (m204): consecutive output tiles land on the
// same XCD so shared A-panels stay in that XCD's L2.
__device__ __forceinline__ int swz_tile(int v, int total) {
    int q = total >> 3, r = total & 7;
    int x = v & 7, k = v >> 3;
    int b = (x < r) ? x * (q + 1) : r * (q + 1) + (x - r) * q;
    return b + k;
}

// branch-free expert lookup: e = #{i in [1,En) : tb[i] <= tile}
__device__ __forceinline__ int find_e(const int* __restrict__ tb, int tile) {
    int e = 0;
#pragma unroll
    for (int i = 1; i < En; i++) e += (tb[i] <= tile) ? 1 : 0;
    return e;
}

// ---------------- gate: logits -> top2 -> softmax -> slot assignment --------
__global__ __launch_bounds__(256) void gate_kernel(
    const float* __restrict__ x, const float* __restrict__ Wg,
    const float* __restrict__ bg,
    int* cnt, int* tok_e, int* tok_pos, float* tok_w)
{
    int t = blockIdx.x;
    int tid = threadIdx.x;
    __shared__ float part[256][17];
    __shared__ float logits[16];

    float p[16];
#pragma unroll
    for (int e = 0; e < 16; e++) p[e] = 0.f;

    float4 xv = *reinterpret_cast<const float4*>(x + (size_t)t * Dn + tid * 4);
    float xs[4] = {xv.x, xv.y, xv.z, xv.w};
#pragma unroll
    for (int j = 0; j < 4; j++) {
        int row = tid * 4 + j;
        const float4* wrow = reinterpret_cast<const float4*>(Wg + (size_t)row * 16);
#pragma unroll
        for (int q = 0; q < 4; q++) {
            float4 w4 = wrow[q];
            p[q * 4 + 0] += xs[j] * w4.x;
            p[q * 4 + 1] += xs[j] * w4.y;
            p[q * 4 + 2] += xs[j] * w4.z;
            p[q * 4 + 3] += xs[j] * w4.w;
        }
    }
#pragma unroll
    for (int e = 0; e < 16; e++) part[tid][e] = p[e];
    __syncthreads();
    for (int off = 128; off > 0; off >>= 1) {
        if (tid < off) {
#pragma unroll
            for (int e = 0; e < 16; e++) part[tid][e] += part[tid + off][e];
        }
        __syncthreads();
    }
    if (tid < 16) logits[tid] = part[0][tid] + bg[tid];
    __syncthreads();
    if (tid == 0) {
        float v0 = -1e30f, v1 = -1e30f; int i0 = -1, i1 = -1;
        for (int e = 0; e < 16; e++) { float v = logits[e]; if (v > v0) { v0 = v; i0 = e; } }
        for (int e = 0; e < 16; e++) { if (e == i0) continue; float v = logits[e]; if (v > v1) { v1 = v; i1 = e; } }
        float ex = __expf(v1 - v0);
        float w0 = 1.f / (1.f + ex);
        float w1 = ex / (1.f + ex);
        int p0 = atomicAdd(&cnt[i0], 1);
        int p1 = atomicAdd(&cnt[i1], 1);
        tok_e[t * 2 + 0] = i0; tok_e[t * 2 + 1] = i1;
        tok_pos[t * 2 + 0] = p0; tok_pos[t * 2 + 1] = p1;
        tok_w[t * 2 + 0] = w0; tok_w[t * 2 + 1] = w1;
    }
}

// ---------------- scan: row bases + tile bases ------------------------------
__global__ void scan_kernel(const int* cnt, int* base, int* tb1, int* tb2)
{
    if (threadIdx.x == 0 && blockIdx.x == 0) {
        int b = 0, a1 = 0, a2 = 0;
        for (int e = 0; e < En; e++) {
            base[e] = b; tb1[e] = a1; tb2[e] = a2;
            int c = cnt[e];
            int mt = (c + 127) >> 7;
            b += c; a1 += mt * (Hn / 128); a2 += mt * (Dn / 128);
        }
        base[En] = b; tb1[En] = a1; tb2[En] = a2;
    }
}

// ---------------- gather: x -> xg (bf16, expert-contiguous rows) ------------
__global__ __launch_bounds__(256) void gather_kernel(
    const float* __restrict__ x, const int* tok_e, const int* tok_pos,
    const int* base, unsigned short* xg)
{
    int t = blockIdx.x; int tid = threadIdx.x;
    int e0 = tok_e[2 * t], e1 = tok_e[2 * t + 1];
    int r0 = base[e0] + tok_pos[2 * t];
    int r1 = base[e1] + tok_pos[2 * t + 1];
    float4 v = *reinterpret_cast<const float4*>(x + (size_t)t * Dn + tid * 4);
    ushort4 u;
    u.x = f2bf(v.x); u.y = f2bf(v.y); u.z = f2bf(v.z); u.w = f2bf(v.w);
    *reinterpret_cast<ushort4*>(xg + (size_t)r0 * Dn + tid * 4) = u;
    *reinterpret_cast<ushort4*>(xg + (size_t)r1 * Dn + tid * 4) = u;
}

// ---------------- convert + transpose weights: [R][C] f32 -> [C][R] bf16 ----
__global__ __launch_bounds__(256) void convT_kernel(
    const float* __restrict__ src, unsigned short* __restrict__ dst, int R, int C)
{
    int e = blockIdx.z;
    const float* s = src + (size_t)e * R * C;
    unsigned short* d = dst + (size_t)e * R * C;
    __shared__ float tile[32][33];
    int r0 = blockIdx.y * 32, c0 = blockIdx.x * 32;
    int tr = threadIdx.x >> 3;
    int tc4 = (threadIdx.x & 7) * 4;
    float4 v = *reinterpret_cast<const float4*>(s + (size_t)(r0 + tr) * C + c0 + tc4);
    tile[tr][tc4 + 0] = v.x; tile[tr][tc4 + 1] = v.y;
    tile[tr][tc4 + 2] = v.z; tile[tr][tc4 + 3] = v.w;
    __syncthreads();
    int oc = tr;
    int or4 = tc4;
    ushort4 u;
    u.x = f2bf(tile[or4 + 0][oc]);
    u.y = f2bf(tile[or4 + 1][oc]);
    u.z = f2bf(tile[or4 + 2][oc]);
    u.w = f2bf(tile[or4 + 3][oc]);
    *reinterpret_cast<ushort4*>(d + (size_t)(c0 + oc) * R + r0 + or4) = u;
}

// ---------------- GEMM1: hg = relu(xg @ W1 + b1), bf16 out ------------------
__global__ __launch_bounds__(256) void gemm1_kernel(
    const unsigned short* __restrict__ xg, const unsigned short* __restrict__ w1t,
    const float* __restrict__ b1, unsigned short* __restrict__ hg,
    const int* __restrict__ cnt, const int* __restrict__ base,
    const int* __restrict__ tb)
{
    __shared__ unsigned short ldsA[128 * 32];
    __shared__ unsigned short ldsB[128 * 32];
    int tid = threadIdx.x;
    int total = tb[En];
    for (int v = blockIdx.x; v < total; v += gridDim.x) {
        int tile = swz_tile(v, total);
        int e = find_e(tb, tile);
        int local = tile - tb[e];
        int mtile = local >> 5;          // Hn/128 = 32 n-tiles (inner)
        int ntile = local & 31;
        int M_e = cnt[e];
        int m0 = mtile * 128, n0 = ntile * 128;
        int rowbase0 = base[e] + m0;
        const unsigned short* Ab = xg + (size_t)rowbase0 * Dn;
        const unsigned short* Bb = w1t + (size_t)e * Hn * Dn + (size_t)n0 * Dn;

        f32x4 acc[4][4];
#pragma unroll
        for (int m = 0; m < 4; m++)
#pragma unroll
            for (int n = 0; n < 4; n++) acc[m][n] = (f32x4){0.f, 0.f, 0.f, 0.f};

        int lane = tid & 63, wid = tid >> 6;
        int wm = (wid >> 1) * 64, wn = (wid & 1) * 64;
        int lr16 = lane & 15, lk = lane >> 4;

        for (int k0 = 0; k0 < Dn; k0 += 32) {
            __syncthreads();
#pragma unroll
            for (int i = 0; i < 2; i++) {
                int c = tid + i * 256;
                int row = c >> 2, col = c & 3;
                gload_lds16(Ab + (size_t)row * Dn + k0 + col * 8, (char*)ldsA + c * 16);
                gload_lds16(Bb + (size_t)row * Dn + k0 + col * 8, (char*)ldsB + c * 16);
            }
            __syncthreads();
            bf16x8 a[4], b[4];
#pragma unroll
            for (int m = 0; m < 4; m++)
                a[m] = *(const bf16x8*)(ldsA + (wm + m * 16 + lr16) * 32 + lk * 8);
#pragma unroll
            for (int n = 0; n < 4; n++)
                b[n] = *(const bf16x8*)(ldsB + (wn + n * 16 + lr16) * 32 + lk * 8);
#pragma unroll
            for (int m = 0; m < 4; m++)
#pragma unroll
                for (int n = 0; n < 4; n++)
                    acc[m][n] = __builtin_amdgcn_mfma_f32_16x16x32_bf16(a[m], b[n], acc[m][n], 0, 0, 0);
        }
        __syncthreads();
        const float* b1e = b1 + (size_t)e * Hn;
        int lj = (lane >> 4) * 4;
#pragma unroll
        for (int n = 0; n < 4; n++) {
            int col = n0 + wn + n * 16 + lr16;
            float bias = b1e[col];
#pragma unroll
            for (int m = 0; m < 4; m++) {
#pragma unroll
                for (int j = 0; j < 4; j++) {
                    int rl = wm + m * 16 + lj + j;
                    if (m0 + rl < M_e) {
                        float vv = fmaxf(acc[m][n][j] + bias, 0.f);
                        hg[(size_t)(rowbase0 + rl) * Hn + col] = f2bf(vv);
                    }
                }
            }
        }
    }
}

// ---------------- GEMM2: y[row] = hg[row] @ W2[e] + b2[e] (f32, coalesced) --
__global__ __launch_bounds__(256) void gemm2_kernel(
    const unsigned short* __restrict__ hg, const unsigned short* __restrict__ w2t,
    const float* __restrict__ b2, float* __restrict__ y,
    const int* __restrict__ cnt, const int* __restrict__ base,
    const int* __restrict__ tb)
{
    __shared__ unsigned short ldsA[128 * 32];
    __shared__ unsigned short ldsB[128 * 32];
    int tid = threadIdx.x;
    int total = tb[En];
    for (int v = blockIdx.x; v < total; v += gridDim.x) {
        int tile = swz_tile(v, total);
        int e = find_e(tb, tile);
        int local = tile - tb[e];
        int mtile = local >> 3;          // Dn/128 = 8 n-tiles (inner)
        int ntile = local & 7;
        int M_e = cnt[e];
        int m0 = mtile * 128, n0 = ntile * 128;
        int rowbase0 = base[e] + m0;
        const unsigned short* Ab = hg + (size_t)rowbase0 * Hn;
        const unsigned short* Bb = w2t + (size_t)e * Dn * Hn + (size_t)n0 * Hn;

        f32x4 acc[4][4];
#pragma unroll
        for (int m = 0; m < 4; m++)
#pragma unroll
            for (int n = 0; n < 4; n++) acc[m][n] = (f32x4){0.f, 0.f, 0.f, 0.f};

        int lane = tid & 63, wid = tid >> 6;
        int wm = (wid >> 1) * 64, wn = (wid & 1) * 64;
        int lr16 = lane & 15, lk = lane >> 4;

        for (int k0 = 0; k0 < Hn; k0 += 32) {
            __syncthreads();
#pragma unroll
            for (int i = 0; i < 2; i++) {
                int c = tid + i * 256;
                int row = c >> 2, col = c & 3;
                gload_lds16(Ab + (size_t)row * Hn + k0 + col * 8, (char*)ldsA + c * 16);
                gload_lds16(Bb + (size_t)row * Hn + k0 + col * 8, (char*)ldsB + c * 16);
            }
            __syncthreads();
            bf16x8 a[4], b[4];
#pragma unroll
            for (int m = 0; m < 4; m++)
                a[m] = *(const bf16x8*)(ldsA + (wm + m * 16 + lr16) * 32 + lk * 8);
#pragma unroll
            for (int n = 0; n < 4; n++)
                b[n] = *(const bf16x8*)(ldsB + (wn + n * 16 + lr16) * 32 + lk * 8);
#pragma unroll
            for (int m = 0; m < 4; m++)
#pragma unroll
                for (int n = 0; n < 4; n++)
                    acc[m][n] = __builtin_amdgcn_mfma_f32_16x16x32_bf16(a[m], b[n], acc[m][n], 0, 0, 0);
        }
        __syncthreads();
        const float* b2e = b2 + (size_t)e * Dn;
        int lj = (lane >> 4) * 4;
#pragma unroll
        for (int n = 0; n < 4; n++) {
            int col = n0 + wn + n * 16 + lr16;
            float bias = b2e[col];
#pragma unroll
            for (int m = 0; m < 4; m++) {
#pragma unroll
                for (int j = 0; j < 4; j++) {
                    int rl = wm + m * 16 + lj + j;
                    if (m0 + rl < M_e) {
                        y[(size_t)(rowbase0 + rl) * Dn + col] = acc[m][n][j] + bias;
                    }
                }
            }
        }
    }
}

// ---------------- combine: out[t] = w0*y[r0] + w1*y[r1] ---------------------
__global__ __launch_bounds__(256) void combine_kernel(
    const float* __restrict__ y, const int* __restrict__ tok_e,
    const int* __restrict__ tok_pos, const int* __restrict__ base,
    const float* __restrict__ tok_w, float* __restrict__ out)
{
    int t = blockIdx.x, tid = threadIdx.x;
    int e0 = tok_e[2 * t], e1 = tok_e[2 * t + 1];
    int r0 = base[e0] + tok_pos[2 * t];
    int r1 = base[e1] + tok_pos[2 * t + 1];
    float w0 = tok_w[2 * t], w1 = tok_w[2 * t + 1];
    float4 a = *reinterpret_cast<const float4*>(y + (size_t)r0 * Dn + tid * 4);
    float4 b = *reinterpret_cast<const float4*>(y + (size_t)r1 * Dn + tid * 4);
    float4 o;
    o.x = w0 * a.x + w1 * b.x;
    o.y = w0 * a.y + w1 * b.y;
    o.z = w0 * a.z + w1 * b.z;
    o.w = w0 * a.w + w1 * b.w;
    *reinterpret_cast<float4*>(out + (size_t)t * Dn + tid * 4) = o;
}

// ---------------- launch ----------------------------------------------------
extern "C" void kernel_launch(void* const* d_in, const int* in_sizes, int n_in,
                              void* d_out, int out_size, void* d_ws, size_t ws_size,
                              hipStream_t stream)
{
    const float* x  = (const float*)d_in[0];
    const float* Wg = (const float*)d_in[1];
    const float* bg = (const float*)d_in[2];
    const float* W1 = (const float*)d_in[3];
    const float* b1 = (const float*)d_in[4];
    const float* W2 = (const float*)d_in[5];
    const float* b2 = (const float*)d_in[6];
    float* out = (float*)d_out;

    char* ws = (char*)d_ws;
    size_t off = 0;
    auto alloc = [&](size_t bytes) {
        size_t o = off; off += (bytes + 255) & ~(size_t)255; return o;
    };
    const int ROWS = Tn * 2;            // 16384 dispatch rows
    const int RCAP = ROWS + 128;        // slack for padded tile reads/writes

    unsigned short* Wt = (unsigned short*)(ws + alloc((size_t)En * Hn * Dn * 2)); // W1t then W2t
    unsigned short* xg = (unsigned short*)(ws + alloc((size_t)RCAP * Dn * 2));
    unsigned short* hg = (unsigned short*)(ws + alloc((size_t)RCAP * Hn * 2));
    float* yv      = (float*)(ws + alloc((size_t)RCAP * Dn * 4));
    int*   cnt     = (int*)(ws + alloc(En * 4));
    int*   base    = (int*)(ws + alloc((En + 1) * 4));
    int*   tb1     = (int*)(ws + alloc((En + 1) * 4));
    int*   tb2     = (int*)(ws + alloc((En + 1) * 4));
    int*   tok_e   = (int*)(ws + alloc(Tn * 2 * 4));
    int*   tok_pos = (int*)(ws + alloc(Tn * 2 * 4));
    float* tok_w   = (float*)(ws + alloc(Tn * 2 * 4));
    (void)ws_size; (void)in_sizes; (void)n_in; (void)out_size;

    hipMemsetAsync(cnt, 0, En * 4, stream);

    gate_kernel<<<Tn, 256, 0, stream>>>(x, Wg, bg, cnt, tok_e, tok_pos, tok_w);
    scan_kernel<<<1, 64, 0, stream>>>(cnt, base, tb1, tb2);
    gather_kernel<<<Tn, 256, 0, stream>>>(x, tok_e, tok_pos, base, xg);

    // W1 [E][Dn][Hn] -> Wt [E][Hn][Dn] bf16
    convT_kernel<<<dim3(Hn / 32, Dn / 32, En), 256, 0, stream>>>(W1, Wt, Dn, Hn);
    // worst-case tiles: sum ceil(c/128)<=144 -> 144*32 = 4608
    gemm1_kernel<<<4608, 256, 0, stream>>>(xg, Wt, b1, hg, cnt, base, tb1);

    // W2 [E][Hn][Dn] -> Wt [E][Dn][Hn] bf16 (Wt reused; stream-ordered)
    convT_kernel<<<dim3(Dn / 32, Hn / 32, En), 256, 0, stream>>>(W2, Wt, Hn, Dn);
    gemm2_kernel<<<1152, 256, 0, stream>>>(hg, Wt, b2, yv, cnt, base, tb2);

    combine_kernel<<<Tn, 256, 0, stream>>>(yv, tok_e, tok_pos, base, tok_w, out);
}

// Round 3
// 885.214 us; speedup vs baseline: 1.2490x; 1.2007x over previous
//
#include <hip/hip_runtime.h>
#include <hip/hip_bf16.h>
#include <stdint.h>

// MoE: T=8192, D=1024, H=4096, E=16, top-2. Sparse dispatch + bf16 MFMA GEMMs.
// GEMMs: ring-4 LDS pipeline, BK=32, counted vmcnt (never 0 in steady state),
// one raw s_barrier per K-tile, T2 XOR swizzle (conflict-free ds_read_b128).

#define Tn 8192
#define Dn 1024
#define Hn 4096
#define En 16

typedef __attribute__((ext_vector_type(8))) short bf16x8;
typedef __attribute__((ext_vector_type(4))) float f32x4;

__device__ __forceinline__ unsigned short f2bf(float f) {
    union { __hip_bfloat16 h; unsigned short u; } cv;
    cv.h = __float2bfloat16(f);
    return cv.u;
}

__device__ __forceinline__ void gload_lds16(const void* gptr, void* lptr) {
    __builtin_amdgcn_global_load_lds(
        (const __attribute__((address_space(1))) uint32_t*)gptr,
        (__attribute__((address_space(3))) uint32_t*)lptr, 16, 0, 0);
}

// bijective XCD-chunked swizzle (m204)
__device__ __forceinline__ int swz_tile(int v, int total) {
    int q = total >> 3, r = total & 7;
    int x = v & 7, k = v >> 3;
    int b = (x < r) ? x * (q + 1) : r * (q + 1) + (x - r) * q;
    return b + k;
}

__device__ __forceinline__ int find_e(const int* __restrict__ tb, int tile) {
    int e = 0;
#pragma unroll
    for (int i = 1; i < En; i++) e += (tb[i] <= tile) ? 1 : 0;
    return e;
}

template<int N> __device__ __forceinline__ void waitvm() {
    if constexpr (N == 8)      asm volatile("s_waitcnt vmcnt(8)" ::: "memory");
    else if constexpr (N == 6) asm volatile("s_waitcnt vmcnt(6)" ::: "memory");
    else if constexpr (N == 4) asm volatile("s_waitcnt vmcnt(4)" ::: "memory");
    else if constexpr (N == 3) asm volatile("s_waitcnt vmcnt(3)" ::: "memory");
    else                       asm volatile("s_waitcnt vmcnt(0)" ::: "memory");
}
__device__ __forceinline__ void barrier_raw() {
    asm volatile("s_barrier" ::: "memory");
}

// ---------------- gate ------------------------------------------------------
__global__ __launch_bounds__(256) void gate_kernel(
    const float* __restrict__ x, const float* __restrict__ Wg,
    const float* __restrict__ bg,
    int* cnt, int* tok_e, int* tok_pos, float* tok_w)
{
    int t = blockIdx.x;
    int tid = threadIdx.x;
    __shared__ float part[256][17];
    __shared__ float logits[16];

    float p[16];
#pragma unroll
    for (int e = 0; e < 16; e++) p[e] = 0.f;

    float4 xv = *reinterpret_cast<const float4*>(x + (size_t)t * Dn + tid * 4);
    float xs[4] = {xv.x, xv.y, xv.z, xv.w};
#pragma unroll
    for (int j = 0; j < 4; j++) {
        int row = tid * 4 + j;
        const float4* wrow = reinterpret_cast<const float4*>(Wg + (size_t)row * 16);
#pragma unroll
        for (int q = 0; q < 4; q++) {
            float4 w4 = wrow[q];
            p[q * 4 + 0] += xs[j] * w4.x;
            p[q * 4 + 1] += xs[j] * w4.y;
            p[q * 4 + 2] += xs[j] * w4.z;
            p[q * 4 + 3] += xs[j] * w4.w;
        }
    }
#pragma unroll
    for (int e = 0; e < 16; e++) part[tid][e] = p[e];
    __syncthreads();
    for (int off = 128; off > 0; off >>= 1) {
        if (tid < off) {
#pragma unroll
            for (int e = 0; e < 16; e++) part[tid][e] += part[tid + off][e];
        }
        __syncthreads();
    }
    if (tid < 16) logits[tid] = part[0][tid] + bg[tid];
    __syncthreads();
    if (tid == 0) {
        float v0 = -1e30f, v1 = -1e30f; int i0 = -1, i1 = -1;
        for (int e = 0; e < 16; e++) { float v = logits[e]; if (v > v0) { v0 = v; i0 = e; } }
        for (int e = 0; e < 16; e++) { if (e == i0) continue; float v = logits[e]; if (v > v1) { v1 = v; i1 = e; } }
        float ex = __expf(v1 - v0);
        float w0 = 1.f / (1.f + ex);
        float w1 = ex / (1.f + ex);
        int p0 = atomicAdd(&cnt[i0], 1);
        int p1 = atomicAdd(&cnt[i1], 1);
        tok_e[t * 2 + 0] = i0; tok_e[t * 2 + 1] = i1;
        tok_pos[t * 2 + 0] = p0; tok_pos[t * 2 + 1] = p1;
        tok_w[t * 2 + 0] = w0; tok_w[t * 2 + 1] = w1;
    }
}

// ---------------- scan ------------------------------------------------------
__global__ void scan_kernel(const int* cnt, int* base, int* tb1, int* tb2)
{
    if (threadIdx.x == 0 && blockIdx.x == 0) {
        int b = 0, a1 = 0, a2 = 0;
        for (int e = 0; e < En; e++) {
            base[e] = b; tb1[e] = a1; tb2[e] = a2;
            int c = cnt[e];
            b += c;
            a1 += ((c + 255) >> 8) * (Hn / 256);   // gemm1: BM=256, BN=256
            a2 += ((c + 127) >> 7) * (Dn / 256);   // gemm2: BM=128, BN=256
        }
        base[En] = b; tb1[En] = a1; tb2[En] = a2;
    }
}

// ---------------- gather ----------------------------------------------------
__global__ __launch_bounds__(256) void gather_kernel(
    const float* __restrict__ x, const int* tok_e, const int* tok_pos,
    const int* base, unsigned short* xg)
{
    int t = blockIdx.x; int tid = threadIdx.x;
    int e0 = tok_e[2 * t], e1 = tok_e[2 * t + 1];
    int r0 = base[e0] + tok_pos[2 * t];
    int r1 = base[e1] + tok_pos[2 * t + 1];
    float4 v = *reinterpret_cast<const float4*>(x + (size_t)t * Dn + tid * 4);
    ushort4 u;
    u.x = f2bf(v.x); u.y = f2bf(v.y); u.z = f2bf(v.z); u.w = f2bf(v.w);
    *reinterpret_cast<ushort4*>(xg + (size_t)r0 * Dn + tid * 4) = u;
    *reinterpret_cast<ushort4*>(xg + (size_t)r1 * Dn + tid * 4) = u;
}

// ---------------- convT: [R][C] f32 -> [C][R] bf16 --------------------------
__global__ __launch_bounds__(256) void convT_kernel(
    const float* __restrict__ src, unsigned short* __restrict__ dst, int R, int C)
{
    int e = blockIdx.z;
    const float* s = src + (size_t)e * R * C;
    unsigned short* d = dst + (size_t)e * R * C;
    __shared__ float tile[32][33];
    int r0 = blockIdx.y * 32, c0 = blockIdx.x * 32;
    int tr = threadIdx.x >> 3;
    int tc4 = (threadIdx.x & 7) * 4;
    float4 v = *reinterpret_cast<const float4*>(s + (size_t)(r0 + tr) * C + c0 + tc4);
    tile[tr][tc4 + 0] = v.x; tile[tr][tc4 + 1] = v.y;
    tile[tr][tc4 + 2] = v.z; tile[tr][tc4 + 3] = v.w;
    __syncthreads();
    int oc = tr;
    int or4 = tc4;
    ushort4 u;
    u.x = f2bf(tile[or4 + 0][oc]);
    u.y = f2bf(tile[or4 + 1][oc]);
    u.z = f2bf(tile[or4 + 2][oc]);
    u.w = f2bf(tile[or4 + 3][oc]);
    *reinterpret_cast<ushort4*>(d + (size_t)(c0 + oc) * R + r0 + or4) = u;
}

// ---------------- pipelined GEMM (ring-4, BK=32, counted vmcnt) -------------
// C-tile = BM x 256, 512 threads (8 waves, 2Mx4N). One output tile per block.
// G1: out = relu(A@B^T + bias) as bf16 (stride NBROWS). else: f32 out + bias.
template<int BM, int KDIM, int NBROWS, int NSH, bool G1>
__global__ __launch_bounds__(512, 2) void gemmp_kernel(
    const unsigned short* __restrict__ Ag, const unsigned short* __restrict__ Bg,
    const float* __restrict__ bias, unsigned short* __restrict__ outb,
    float* __restrict__ outf,
    const int* __restrict__ cnt, const int* __restrict__ base,
    const int* __restrict__ tb)
{
    constexpr int MR = BM / 32;          // m-frags per wave (wave rows = BM/2)
    constexpr int NT = KDIM / 32;        // K-tiles (>= 4)
    constexpr int L  = BM / 128 + 2;     // gloads per thread per K-tile
    constexpr int ASLOT = BM * 32;       // elems
    constexpr int BSLOT = 256 * 32;
    constexpr int SLOT = ASLOT + BSLOT;
    __shared__ unsigned short lds[4 * SLOT];

    int total = tb[En];
    int v = blockIdx.x;
    if (v >= total) return;
    int tile = swz_tile(v, total);
    int e = find_e(tb, tile);
    int local = tile - tb[e];
    int mtile = local >> NSH, ntile = local & ((1 << NSH) - 1);
    int M_e = cnt[e];
    int m0 = mtile * BM, n0 = ntile * 256;
    int rowbase0 = base[e] + m0;
    const unsigned short* Ab = Ag + (size_t)rowbase0 * KDIM;
    const unsigned short* Bb = Bg + (size_t)e * NBROWS * KDIM + (size_t)n0 * KDIM;

    int tid = threadIdx.x;
    int lane = tid & 63;
    int wid = tid >> 6;
    int wr = wid >> 2, wc = wid & 3;
    int lr16 = lane & 15, lk = lane >> 4;

    // staging source addrs (global pre-swizzled so linear LDS dest ends up
    // XOR-swizzled; read side applies the same involution)
    int ja0 = tid;        int ra0 = ja0 >> 2; int ca0 = (ja0 & 3) ^ ((ra0 >> 1) & 3);
    int ja1 = tid + 512;  int ra1 = ja1 >> 2; int ca1 = (ja1 & 3) ^ ((ra1 >> 1) & 3);
    int jb0 = tid;        int rb0 = jb0 >> 2; int cb0 = (jb0 & 3) ^ ((rb0 >> 1) & 3);
    int jb1 = tid + 512;  int rb1 = jb1 >> 2; int cb1 = (jb1 & 3) ^ ((rb1 >> 1) & 3);
    const unsigned short* aSrc0 = Ab + (size_t)ra0 * KDIM + ca0 * 8;
    const unsigned short* aSrc1 = Ab + (size_t)ra1 * KDIM + ca1 * 8;
    const unsigned short* bSrc0 = Bb + (size_t)rb0 * KDIM + cb0 * 8;
    const unsigned short* bSrc1 = Bb + (size_t)rb1 * KDIM + cb1 * 8;

    // fragment LDS offsets (elems, slot-relative), swizzled
    int aoff[MR], boff[4];
#pragma unroll
    for (int m = 0; m < MR; m++) {
        int row = wr * (BM / 2) + m * 16 + lr16;
        aoff[m] = row * 32 + ((lk ^ ((row >> 1) & 3)) << 3);
    }
#pragma unroll
    for (int n = 0; n < 4; n++) {
        int row = wc * 64 + n * 16 + lr16;
        boff[n] = row * 32 + ((lk ^ ((row >> 1) & 3)) << 3);
    }

    f32x4 acc[MR][4];
#pragma unroll
    for (int m = 0; m < MR; m++)
#pragma unroll
        for (int n = 0; n < 4; n++) acc[m][n] = (f32x4){0.f, 0.f, 0.f, 0.f};

    auto stage = [&](int t) {
        char* sa = (char*)(lds + (size_t)(t & 3) * SLOT);
        char* sb = sa + ASLOT * 2;
        int k0 = t * 32;
        gload_lds16(aSrc0 + k0, sa + ja0 * 16);
        if constexpr (BM == 256) gload_lds16(aSrc1 + k0, sa + ja1 * 16);
        gload_lds16(bSrc0 + k0, sb + jb0 * 16);
        gload_lds16(bSrc1 + k0, sb + jb1 * 16);
    };
    auto compute = [&](int t) {
        const unsigned short* sa = lds + (size_t)(t & 3) * SLOT;
        const unsigned short* sb = sa + ASLOT;
        bf16x8 a[MR], b[4];
#pragma unroll
        for (int m = 0; m < MR; m++) a[m] = *(const bf16x8*)(sa + aoff[m]);
#pragma unroll
        for (int n = 0; n < 4; n++) b[n] = *(const bf16x8*)(sb + boff[n]);
        __builtin_amdgcn_s_setprio(1);
#pragma unroll
        for (int m = 0; m < MR; m++)
#pragma unroll
            for (int n = 0; n < 4; n++)
                acc[m][n] = __builtin_amdgcn_mfma_f32_16x16x32_bf16(a[m], b[n], acc[m][n], 0, 0, 0);
        __builtin_amdgcn_s_setprio(0);
    };

    // prologue: 3 K-tiles in flight
    stage(0); stage(1); stage(2);

    for (int t = 0; t < NT - 3; ++t) {
        waitvm<2 * L>();        // S(t) landed; S(t+1),S(t+2) stay in flight
        barrier_raw();
        stage(t + 3);
        compute(t);
    }
    waitvm<2 * L>(); barrier_raw(); compute(NT - 3);
    waitvm<L>();     barrier_raw(); compute(NT - 2);
    waitvm<0>();     barrier_raw(); compute(NT - 1);

    // epilogue
    const float* be = bias + (size_t)e * NBROWS;
    int lj = (lane >> 4) * 4;
#pragma unroll
    for (int n = 0; n < 4; n++) {
        int col = n0 + wc * 64 + n * 16 + lr16;
        float bs = be[col];
#pragma unroll
        for (int m = 0; m < MR; m++) {
#pragma unroll
            for (int j = 0; j < 4; j++) {
                int rt = wr * (BM / 2) + m * 16 + lj + j;
                if (m0 + rt < M_e) {
                    float vv = acc[m][n][j] + bs;
                    if constexpr (G1)
                        outb[(size_t)(rowbase0 + rt) * NBROWS + col] = f2bf(fmaxf(vv, 0.f));
                    else
                        outf[(size_t)(rowbase0 + rt) * NBROWS + col] = vv;
                }
            }
        }
    }
}

// ---------------- combine ---------------------------------------------------
__global__ __launch_bounds__(256) void combine_kernel(
    const float* __restrict__ y, const int* __restrict__ tok_e,
    const int* __restrict__ tok_pos, const int* __restrict__ base,
    const float* __restrict__ tok_w, float* __restrict__ out)
{
    int t = blockIdx.x, tid = threadIdx.x;
    int e0 = tok_e[2 * t], e1 = tok_e[2 * t + 1];
    int r0 = base[e0] + tok_pos[2 * t];
    int r1 = base[e1] + tok_pos[2 * t + 1];
    float w0 = tok_w[2 * t], w1 = tok_w[2 * t + 1];
    float4 a = *reinterpret_cast<const float4*>(y + (size_t)r0 * Dn + tid * 4);
    float4 b = *reinterpret_cast<const float4*>(y + (size_t)r1 * Dn + tid * 4);
    float4 o;
    o.x = w0 * a.x + w1 * b.x;
    o.y = w0 * a.y + w1 * b.y;
    o.z = w0 * a.z + w1 * b.z;
    o.w = w0 * a.w + w1 * b.w;
    *reinterpret_cast<float4*>(out + (size_t)t * Dn + tid * 4) = o;
}

// ---------------- launch ----------------------------------------------------
extern "C" void kernel_launch(void* const* d_in, const int* in_sizes, int n_in,
                              void* d_out, int out_size, void* d_ws, size_t ws_size,
                              hipStream_t stream)
{
    const float* x  = (const float*)d_in[0];
    const float* Wg = (const float*)d_in[1];
    const float* bg = (const float*)d_in[2];
    const float* W1 = (const float*)d_in[3];
    const float* b1 = (const float*)d_in[4];
    const float* W2 = (const float*)d_in[5];
    const float* b2 = (const float*)d_in[6];
    float* out = (float*)d_out;

    char* ws = (char*)d_ws;
    size_t off = 0;
    auto alloc = [&](size_t bytes) {
        size_t o = off; off += (bytes + 255) & ~(size_t)255; return o;
    };
    const int ROWS = Tn * 2;            // 16384 dispatch rows
    const int RCAP = ROWS + 256;        // slack for 256-row tile overreads

    unsigned short* Wt = (unsigned short*)(ws + alloc((size_t)En * Hn * Dn * 2)); // W1t then W2t
    unsigned short* xg = (unsigned short*)(ws + alloc((size_t)RCAP * Dn * 2));
    unsigned short* hg = (unsigned short*)(ws + alloc((size_t)RCAP * Hn * 2));
    float* yv      = (float*)(ws + alloc((size_t)RCAP * Dn * 4));
    int*   cnt     = (int*)(ws + alloc(En * 4));
    int*   base    = (int*)(ws + alloc((En + 1) * 4));
    int*   tb1     = (int*)(ws + alloc((En + 1) * 4));
    int*   tb2     = (int*)(ws + alloc((En + 1) * 4));
    int*   tok_e   = (int*)(ws + alloc(Tn * 2 * 4));
    int*   tok_pos = (int*)(ws + alloc(Tn * 2 * 4));
    float* tok_w   = (float*)(ws + alloc(Tn * 2 * 4));
    (void)ws_size; (void)in_sizes; (void)n_in; (void)out_size;

    hipMemsetAsync(cnt, 0, En * 4, stream);

    gate_kernel<<<Tn, 256, 0, stream>>>(x, Wg, bg, cnt, tok_e, tok_pos, tok_w);
    scan_kernel<<<1, 64, 0, stream>>>(cnt, base, tb1, tb2);
    gather_kernel<<<Tn, 256, 0, stream>>>(x, tok_e, tok_pos, base, xg);

    // W1 [E][Dn][Hn] -> Wt [E][Hn][Dn] bf16
    convT_kernel<<<dim3(Hn / 32, Dn / 32, En), 256, 0, stream>>>(W1, Wt, Dn, Hn);
    // gemm1: BM=256, BN=256, K=1024. worst tiles = 80 * 16 = 1280
    gemmp_kernel<256, Dn, Hn, 4, true><<<1280, 512, 0, stream>>>(
        xg, Wt, b1, hg, nullptr, cnt, base, tb1);

    // W2 [E][Hn][Dn] -> Wt [E][Dn][Hn] bf16
    convT_kernel<<<dim3(Dn / 32, Hn / 32, En), 256, 0, stream>>>(W2, Wt, Hn, Dn);
    // gemm2: BM=128, BN=256, K=4096. worst tiles = 144 * 4 = 576
    gemmp_kernel<128, Hn, Dn, 2, false><<<576, 512, 0, stream>>>(
        hg, Wt, b2, nullptr, yv, cnt, base, tb2);

    combine_kernel<<<Tn, 256, 0, stream>>>(yv, tok_e, tok_pos, base, tok_w, out);
}

// Round 4
// 879.716 us; speedup vs baseline: 1.2568x; 1.0062x over previous
//
#include <hip/hip_runtime.h>
#include <hip/hip_bf16.h>
#include <stdint.h>

// MoE: T=8192, D=1024, H=4096, E=16, top-2. Sparse dispatch + bf16 MFMA GEMMs.
// GEMMs: 256x256 tile, 8-phase schedule (2 phases per BK=32 sub-tile, ring-4
// LDS), counted vmcnt(8) (never 0 in steady state), raw s_barrier pairs,
// T2 XOR swizzle (0 bank conflicts), setprio around MFMA cluster, swapped
// mfma operands so the epilogue stores 4 consecutive cols per lane (packed).

#define Tn 8192
#define Dn 1024
#define Hn 4096
#define En 16

typedef __attribute__((ext_vector_type(8))) short bf16x8;
typedef __attribute__((ext_vector_type(4))) float f32x4;

__device__ __forceinline__ unsigned short f2bf(float f) {
    union { __hip_bfloat16 h; unsigned short u; } cv;
    cv.h = __float2bfloat16(f);
    return cv.u;
}

__device__ __forceinline__ void gload_lds16(const void* gptr, void* lptr) {
    __builtin_amdgcn_global_load_lds(
        (const __attribute__((address_space(1))) uint32_t*)gptr,
        (__attribute__((address_space(3))) uint32_t*)lptr, 16, 0, 0);
}

// bijective XCD-chunked swizzle (m204)
__device__ __forceinline__ int swz_tile(int v, int total) {
    int q = total >> 3, r = total & 7;
    int x = v & 7, k = v >> 3;
    int b = (x < r) ? x * (q + 1) : r * (q + 1) + (x - r) * q;
    return b + k;
}

__device__ __forceinline__ int find_e(const int* __restrict__ tb, int tile) {
    int e = 0;
#pragma unroll
    for (int i = 1; i < En; i++) e += (tb[i] <= tile) ? 1 : 0;
    return e;
}

__device__ __forceinline__ void waitvm8() { asm volatile("s_waitcnt vmcnt(8)" ::: "memory"); }
__device__ __forceinline__ void waitvm4() { asm volatile("s_waitcnt vmcnt(4)" ::: "memory"); }
__device__ __forceinline__ void waitvm0() { asm volatile("s_waitcnt vmcnt(0)" ::: "memory"); }
__device__ __forceinline__ void waitlgkm0() { asm volatile("s_waitcnt lgkmcnt(0)" ::: "memory"); }
__device__ __forceinline__ void barrier_raw() { asm volatile("s_barrier" ::: "memory"); }

// ---------------- gate ------------------------------------------------------
__global__ __launch_bounds__(256) void gate_kernel(
    const float* __restrict__ x, const float* __restrict__ Wg,
    const float* __restrict__ bg,
    int* cnt, int* tok_e, int* tok_pos, float* tok_w)
{
    int t = blockIdx.x;
    int tid = threadIdx.x;
    __shared__ float part[256][17];
    __shared__ float logits[16];

    float p[16];
#pragma unroll
    for (int e = 0; e < 16; e++) p[e] = 0.f;

    float4 xv = *reinterpret_cast<const float4*>(x + (size_t)t * Dn + tid * 4);
    float xs[4] = {xv.x, xv.y, xv.z, xv.w};
#pragma unroll
    for (int j = 0; j < 4; j++) {
        int row = tid * 4 + j;
        const float4* wrow = reinterpret_cast<const float4*>(Wg + (size_t)row * 16);
#pragma unroll
        for (int q = 0; q < 4; q++) {
            float4 w4 = wrow[q];
            p[q * 4 + 0] += xs[j] * w4.x;
            p[q * 4 + 1] += xs[j] * w4.y;
            p[q * 4 + 2] += xs[j] * w4.z;
            p[q * 4 + 3] += xs[j] * w4.w;
        }
    }
#pragma unroll
    for (int e = 0; e < 16; e++) part[tid][e] = p[e];
    __syncthreads();
    for (int off = 128; off > 0; off >>= 1) {
        if (tid < off) {
#pragma unroll
            for (int e = 0; e < 16; e++) part[tid][e] += part[tid + off][e];
        }
        __syncthreads();
    }
    if (tid < 16) logits[tid] = part[0][tid] + bg[tid];
    __syncthreads();
    if (tid == 0) {
        float v0 = -1e30f, v1 = -1e30f; int i0 = -1, i1 = -1;
        for (int e = 0; e < 16; e++) { float v = logits[e]; if (v > v0) { v0 = v; i0 = e; } }
        for (int e = 0; e < 16; e++) { if (e == i0) continue; float v = logits[e]; if (v > v1) { v1 = v; i1 = e; } }
        float ex = __expf(v1 - v0);
        float w0 = 1.f / (1.f + ex);
        float w1 = ex / (1.f + ex);
        int p0 = atomicAdd(&cnt[i0], 1);
        int p1 = atomicAdd(&cnt[i1], 1);
        tok_e[t * 2 + 0] = i0; tok_e[t * 2 + 1] = i1;
        tok_pos[t * 2 + 0] = p0; tok_pos[t * 2 + 1] = p1;
        tok_w[t * 2 + 0] = w0; tok_w[t * 2 + 1] = w1;
    }
}

// ---------------- scan ------------------------------------------------------
__global__ void scan_kernel(const int* cnt, int* base, int* tb1, int* tb2)
{
    if (threadIdx.x == 0 && blockIdx.x == 0) {
        int b = 0, a1 = 0, a2 = 0;
        for (int e = 0; e < En; e++) {
            base[e] = b; tb1[e] = a1; tb2[e] = a2;
            int c = cnt[e];
            b += c;
            int mt = (c + 255) >> 8;            // BM=256 both GEMMs
            a1 += mt * (Hn / 256);
            a2 += mt * (Dn / 256);
        }
        base[En] = b; tb1[En] = a1; tb2[En] = a2;
    }
}

// ---------------- gather ----------------------------------------------------
__global__ __launch_bounds__(256) void gather_kernel(
    const float* __restrict__ x, const int* tok_e, const int* tok_pos,
    const int* base, unsigned short* xg)
{
    int t = blockIdx.x; int tid = threadIdx.x;
    int e0 = tok_e[2 * t], e1 = tok_e[2 * t + 1];
    int r0 = base[e0] + tok_pos[2 * t];
    int r1 = base[e1] + tok_pos[2 * t + 1];
    float4 v = *reinterpret_cast<const float4*>(x + (size_t)t * Dn + tid * 4);
    ushort4 u;
    u.x = f2bf(v.x); u.y = f2bf(v.y); u.z = f2bf(v.z); u.w = f2bf(v.w);
    *reinterpret_cast<ushort4*>(xg + (size_t)r0 * Dn + tid * 4) = u;
    *reinterpret_cast<ushort4*>(xg + (size_t)r1 * Dn + tid * 4) = u;
}

// ---------------- convT: [R][C] f32 -> [C][R] bf16 --------------------------
__global__ __launch_bounds__(256) void convT_kernel(
    const float* __restrict__ src, unsigned short* __restrict__ dst, int R, int C)
{
    int e = blockIdx.z;
    const float* s = src + (size_t)e * R * C;
    unsigned short* d = dst + (size_t)e * R * C;
    __shared__ float tile[32][33];
    int r0 = blockIdx.y * 32, c0 = blockIdx.x * 32;
    int tr = threadIdx.x >> 3;
    int tc4 = (threadIdx.x & 7) * 4;
    float4 v = *reinterpret_cast<const float4*>(s + (size_t)(r0 + tr) * C + c0 + tc4);
    tile[tr][tc4 + 0] = v.x; tile[tr][tc4 + 1] = v.y;
    tile[tr][tc4 + 2] = v.z; tile[tr][tc4 + 3] = v.w;
    __syncthreads();
    int oc = tr;
    int or4 = tc4;
    ushort4 u;
    u.x = f2bf(tile[or4 + 0][oc]);
    u.y = f2bf(tile[or4 + 1][oc]);
    u.z = f2bf(tile[or4 + 2][oc]);
    u.w = f2bf(tile[or4 + 3][oc]);
    *reinterpret_cast<ushort4*>(d + (size_t)(c0 + oc) * R + r0 + or4) = u;
}

// ---------------- 8-phase GEMM: 256x256 tile, BK=32 ring-4 ------------------
// 512 threads = 8 waves (2M x 4N). Per wave: 128x64 output = 8m x 4n frags.
// Per sub-tile (BK=32): phase1 {ds_read a0-3 + b0-3, stage B(t+3), bar,
// lgkm0, 16 MFMA (m-low), bar}; phase2 {ds_read a4-7, stage A(t+3), bar,
// lgkm0, 16 MFMA (m-high), vmcnt(8/4/0), bar}.
// mfma(b, a, acc): lane&15 = token row, (lane>>4)*4+j = 4 consecutive cols.
template<int KDIM, int NOUT, int NSH, bool G1>
__global__ __launch_bounds__(512, 2) void gemm8p_kernel(
    const unsigned short* __restrict__ Ag, const unsigned short* __restrict__ Bg,
    const float* __restrict__ bias, unsigned short* __restrict__ outb,
    float* __restrict__ outf,
    const int* __restrict__ cnt, const int* __restrict__ base,
    const int* __restrict__ tb)
{
    constexpr int NT = KDIM / 32;        // sub-tiles
    __shared__ unsigned short ldsA[4][256 * 32];
    __shared__ unsigned short ldsB[4][256 * 32];

    int total = tb[En];
    int v = blockIdx.x;
    if (v >= total) return;              // block-uniform exit
    int tile = swz_tile(v, total);
    int e = find_e(tb, tile);
    int local = tile - tb[e];
    int mtile = local >> NSH, ntile = local & ((1 << NSH) - 1);
    int M_e = cnt[e];
    int m0 = mtile * 256, n0 = ntile * 256;
    int rowbase0 = base[e] + m0;
    const unsigned short* Ab = Ag + (size_t)rowbase0 * KDIM;
    const unsigned short* Bb = Bg + (size_t)e * NOUT * KDIM + (size_t)n0 * KDIM;

    int tid = threadIdx.x;
    int lane = tid & 63;
    int wid = tid >> 6;
    int wr = wid >> 2, wc = wid & 3;
    int lr16 = lane & 15, lk = lane >> 4;

    // staging source addrs (global pre-swizzled -> linear LDS dest ends up
    // XOR-swizzled; frag reads apply the same involution). 2 loads per
    // operand sub-tile per thread (rows tid>>2 and (tid+512)>>2).
    int ja0 = tid;        int ra0 = ja0 >> 2; int ca0 = (ja0 & 3) ^ ((ra0 >> 1) & 3);
    int ja1 = tid + 512;  int ra1 = ja1 >> 2; int ca1 = (ja1 & 3) ^ ((ra1 >> 1) & 3);
    const unsigned short* aSrc0 = Ab + (size_t)ra0 * KDIM + ca0 * 8;
    const unsigned short* aSrc1 = Ab + (size_t)ra1 * KDIM + ca1 * 8;
    const unsigned short* bSrc0 = Bb + (size_t)ra0 * KDIM + ca0 * 8;
    const unsigned short* bSrc1 = Bb + (size_t)ra1 * KDIM + ca1 * 8;

    // fragment LDS offsets (elems, slot-relative), swizzled
    int aoff[8], boff[4];
#pragma unroll
    for (int m = 0; m < 8; m++) {
        int row = wr * 128 + m * 16 + lr16;
        aoff[m] = row * 32 + ((lk ^ ((row >> 1) & 3)) << 3);
    }
#pragma unroll
    for (int n = 0; n < 4; n++) {
        int row = wc * 64 + n * 16 + lr16;
        boff[n] = row * 32 + ((lk ^ ((row >> 1) & 3)) << 3);
    }

    f32x4 acc[8][4];
#pragma unroll
    for (int m = 0; m < 8; m++)
#pragma unroll
        for (int n = 0; n < 4; n++) acc[m][n] = (f32x4){0.f, 0.f, 0.f, 0.f};

    auto stageA = [&](int t) {
        char* sa = (char*)ldsA[t & 3];
        int k0 = t * 32;
        gload_lds16(aSrc0 + k0, sa + ja0 * 16);
        gload_lds16(aSrc1 + k0, sa + ja1 * 16);
    };
    auto stageB = [&](int t) {
        char* sb = (char*)ldsB[t & 3];
        int k0 = t * 32;
        gload_lds16(bSrc0 + k0, sb + ja0 * 16);
        gload_lds16(bSrc1 + k0, sb + ja1 * 16);
    };

    // prologue: 3 sub-tiles in flight (B,A interleaved = stream order)
    stageB(0); stageA(0);
    stageB(1); stageA(1);
    stageB(2); stageA(2);
    waitvm8();               // 12 in flight -> sub-tile 0 (A+B) landed
    barrier_raw();

#pragma unroll 4
    for (int t = 0; t < NT; ++t) {
        const unsigned short* sa = ldsA[t & 3];
        const unsigned short* sb = ldsB[t & 3];
        bf16x8 a[4], b[4];
        // ---- phase 1: m-low ----
#pragma unroll
        for (int m = 0; m < 4; m++) a[m] = *(const bf16x8*)(sa + aoff[m]);
#pragma unroll
        for (int n = 0; n < 4; n++) b[n] = *(const bf16x8*)(sb + boff[n]);
        if (t + 3 < NT) stageB(t + 3);
        barrier_raw();
        waitlgkm0();
        __builtin_amdgcn_s_setprio(1);
#pragma unroll
        for (int m = 0; m < 4; m++)
#pragma unroll
            for (int n = 0; n < 4; n++)
                acc[m][n] = __builtin_amdgcn_mfma_f32_16x16x32_bf16(b[n], a[m], acc[m][n], 0, 0, 0);
        __builtin_amdgcn_s_setprio(0);
        barrier_raw();
        // ---- phase 2: m-high ----
#pragma unroll
        for (int m = 0; m < 4; m++) a[m] = *(const bf16x8*)(sa + aoff[m + 4]);
        if (t + 3 < NT) stageA(t + 3);
        barrier_raw();
        waitlgkm0();
        __builtin_amdgcn_s_setprio(1);
#pragma unroll
        for (int m = 0; m < 4; m++)
#pragma unroll
            for (int n = 0; n < 4; n++)
                acc[m + 4][n] = __builtin_amdgcn_mfma_f32_16x16x32_bf16(b[n], a[m], acc[m + 4][n], 0, 0, 0);
        __builtin_amdgcn_s_setprio(0);
        // counted drain guarding sub-tile t+1's reads (8 -> 4 -> 0 tail)
        if (t < NT - 3)       waitvm8();
        else if (t == NT - 3) waitvm4();
        else if (t == NT - 2) waitvm0();
        barrier_raw();
    }

    // ---- epilogue: lane holds row (lr16) x 4 consecutive cols (lj+j) ----
    const float* be = bias + (size_t)e * NOUT;
    int lj = (lane >> 4) * 4;
#pragma unroll
    for (int m = 0; m < 8; m++) {
        int rt = wr * 128 + m * 16 + lr16;
        if (m0 + rt < M_e) {
            size_t rowoff = (size_t)(rowbase0 + rt) * NOUT;
#pragma unroll
            for (int n = 0; n < 4; n++) {
                int col0 = n0 + wc * 64 + n * 16 + lj;
                float4 bs = *reinterpret_cast<const float4*>(be + col0);
                float v0 = acc[m][n][0] + bs.x;
                float v1 = acc[m][n][1] + bs.y;
                float v2 = acc[m][n][2] + bs.z;
                float v3 = acc[m][n][3] + bs.w;
                if constexpr (G1) {
                    ushort4 u;
                    u.x = f2bf(fmaxf(v0, 0.f));
                    u.y = f2bf(fmaxf(v1, 0.f));
                    u.z = f2bf(fmaxf(v2, 0.f));
                    u.w = f2bf(fmaxf(v3, 0.f));
                    *reinterpret_cast<ushort4*>(outb + rowoff + col0) = u;
                } else {
                    float4 o = {v0, v1, v2, v3};
                    *reinterpret_cast<float4*>(outf + rowoff + col0) = o;
                }
            }
        }
    }
}

// ---------------- combine ---------------------------------------------------
__global__ __launch_bounds__(256) void combine_kernel(
    const float* __restrict__ y, const int* __restrict__ tok_e,
    const int* __restrict__ tok_pos, const int* __restrict__ base,
    const float* __restrict__ tok_w, float* __restrict__ out)
{
    int t = blockIdx.x, tid = threadIdx.x;
    int e0 = tok_e[2 * t], e1 = tok_e[2 * t + 1];
    int r0 = base[e0] + tok_pos[2 * t];
    int r1 = base[e1] + tok_pos[2 * t + 1];
    float w0 = tok_w[2 * t], w1 = tok_w[2 * t + 1];
    float4 a = *reinterpret_cast<const float4*>(y + (size_t)r0 * Dn + tid * 4);
    float4 b = *reinterpret_cast<const float4*>(y + (size_t)r1 * Dn + tid * 4);
    float4 o;
    o.x = w0 * a.x + w1 * b.x;
    o.y = w0 * a.y + w1 * b.y;
    o.z = w0 * a.z + w1 * b.z;
    o.w = w0 * a.w + w1 * b.w;
    *reinterpret_cast<float4*>(out + (size_t)t * Dn + tid * 4) = o;
}

// ---------------- launch ----------------------------------------------------
extern "C" void kernel_launch(void* const* d_in, const int* in_sizes, int n_in,
                              void* d_out, int out_size, void* d_ws, size_t ws_size,
                              hipStream_t stream)
{
    const float* x  = (const float*)d_in[0];
    const float* Wg = (const float*)d_in[1];
    const float* bg = (const float*)d_in[2];
    const float* W1 = (const float*)d_in[3];
    const float* b1 = (const float*)d_in[4];
    const float* W2 = (const float*)d_in[5];
    const float* b2 = (const float*)d_in[6];
    float* out = (float*)d_out;

    char* ws = (char*)d_ws;
    size_t off = 0;
    auto alloc = [&](size_t bytes) {
        size_t o = off; off += (bytes + 255) & ~(size_t)255; return o;
    };
    const int ROWS = Tn * 2;            // 16384 dispatch rows
    const int RCAP = ROWS + 256;        // slack for 256-row tile overreads

    unsigned short* Wt = (unsigned short*)(ws + alloc((size_t)En * Hn * Dn * 2)); // W1t then W2t
    unsigned short* xg = (unsigned short*)(ws + alloc((size_t)RCAP * Dn * 2));
    unsigned short* hg = (unsigned short*)(ws + alloc((size_t)RCAP * Hn * 2));
    float* yv      = (float*)(ws + alloc((size_t)RCAP * Dn * 4));
    int*   cnt     = (int*)(ws + alloc(En * 4));
    int*   base    = (int*)(ws + alloc((En + 1) * 4));
    int*   tb1     = (int*)(ws + alloc((En + 1) * 4));
    int*   tb2     = (int*)(ws + alloc((En + 1) * 4));
    int*   tok_e   = (int*)(ws + alloc(Tn * 2 * 4));
    int*   tok_pos = (int*)(ws + alloc(Tn * 2 * 4));
    float* tok_w   = (float*)(ws + alloc(Tn * 2 * 4));
    (void)ws_size; (void)in_sizes; (void)n_in; (void)out_size;

    hipMemsetAsync(cnt, 0, En * 4, stream);

    gate_kernel<<<Tn, 256, 0, stream>>>(x, Wg, bg, cnt, tok_e, tok_pos, tok_w);
    scan_kernel<<<1, 64, 0, stream>>>(cnt, base, tb1, tb2);
    gather_kernel<<<Tn, 256, 0, stream>>>(x, tok_e, tok_pos, base, xg);

    // W1 [E][Dn][Hn] -> Wt [E][Hn][Dn] bf16
    convT_kernel<<<dim3(Hn / 32, Dn / 32, En), 256, 0, stream>>>(W1, Wt, Dn, Hn);
    // gemm1: 256x256, K=1024. worst tiles = 80 * 16 = 1280
    gemm8p_kernel<Dn, Hn, 4, true><<<1280, 512, 0, stream>>>(
        xg, Wt, b1, hg, nullptr, cnt, base, tb1);

    // W2 [E][Hn][Dn] -> Wt [E][Dn][Hn] bf16
    convT_kernel<<<dim3(Dn / 32, Hn / 32, En), 256, 0, stream>>>(W2, Wt, Hn, Dn);
    // gemm2: 256x256, K=4096. worst tiles = 80 * 4 = 320
    gemm8p_kernel<Hn, Dn, 2, false><<<320, 512, 0, stream>>>(
        hg, Wt, b2, nullptr, yv, cnt, base, tb2);

    combine_kernel<<<Tn, 256, 0, stream>>>(yv, tok_e, tok_pos, base, tok_w, out);
}

// Round 5
// 848.565 us; speedup vs baseline: 1.3029x; 1.0367x over previous
//
#include <hip/hip_runtime.h>
#include <hip/hip_bf16.h>
#include <stdint.h>

// MoE: T=8192, D=1024, H=4096, E=16, top-2. Sparse dispatch + bf16 MFMA GEMMs.
// 256x256 8-phase GEMM core (ring-4 BK=32, counted vmcnt, T2 swizzle).
// NEW: XCD-locality tile schedules (gemm1: column-pair per XCD -> B L2-resident;
// gemm2: K-split 2 with (col,khalf) per XCD -> balance + locality).

#define Tn 8192
#define Dn 1024
#define Hn 4096
#define En 16

typedef __attribute__((ext_vector_type(8))) short bf16x8;
typedef __attribute__((ext_vector_type(4))) float f32x4;

__device__ __forceinline__ unsigned short f2bf(float f) {
    union { __hip_bfloat16 h; unsigned short u; } cv;
    cv.h = __float2bfloat16(f);
    return cv.u;
}

__device__ __forceinline__ void gload_lds16(const void* gptr, void* lptr) {
    __builtin_amdgcn_global_load_lds(
        (const __attribute__((address_space(1))) uint32_t*)gptr,
        (__attribute__((address_space(3))) uint32_t*)lptr, 16, 0, 0);
}

// e = #{i in [1,En) : mb[i] <= gm}  (cumulative-mtile lookup, skips empty)
__device__ __forceinline__ int find_e(const int* __restrict__ mb, int gm) {
    int e = 0;
#pragma unroll
    for (int i = 1; i < En; i++) e += (mb[i] <= gm) ? 1 : 0;
    return e;
}

__device__ __forceinline__ void waitvm8() { asm volatile("s_waitcnt vmcnt(8)" ::: "memory"); }
__device__ __forceinline__ void waitvm4() { asm volatile("s_waitcnt vmcnt(4)" ::: "memory"); }
__device__ __forceinline__ void waitvm0() { asm volatile("s_waitcnt vmcnt(0)" ::: "memory"); }
__device__ __forceinline__ void waitlgkm0() { asm volatile("s_waitcnt lgkmcnt(0)" ::: "memory"); }
__device__ __forceinline__ void barrier_raw() { asm volatile("s_barrier" ::: "memory"); }

// ---------------- gate (unchanged: routing determinism) ---------------------
__global__ __launch_bounds__(256) void gate_kernel(
    const float* __restrict__ x, const float* __restrict__ Wg,
    const float* __restrict__ bg,
    int* cnt, int* tok_e, int* tok_pos, float* tok_w)
{
    int t = blockIdx.x;
    int tid = threadIdx.x;
    __shared__ float part[256][17];
    __shared__ float logits[16];

    float p[16];
#pragma unroll
    for (int e = 0; e < 16; e++) p[e] = 0.f;

    float4 xv = *reinterpret_cast<const float4*>(x + (size_t)t * Dn + tid * 4);
    float xs[4] = {xv.x, xv.y, xv.z, xv.w};
#pragma unroll
    for (int j = 0; j < 4; j++) {
        int row = tid * 4 + j;
        const float4* wrow = reinterpret_cast<const float4*>(Wg + (size_t)row * 16);
#pragma unroll
        for (int q = 0; q < 4; q++) {
            float4 w4 = wrow[q];
            p[q * 4 + 0] += xs[j] * w4.x;
            p[q * 4 + 1] += xs[j] * w4.y;
            p[q * 4 + 2] += xs[j] * w4.z;
            p[q * 4 + 3] += xs[j] * w4.w;
        }
    }
#pragma unroll
    for (int e = 0; e < 16; e++) part[tid][e] = p[e];
    __syncthreads();
    for (int off = 128; off > 0; off >>= 1) {
        if (tid < off) {
#pragma unroll
            for (int e = 0; e < 16; e++) part[tid][e] += part[tid + off][e];
        }
        __syncthreads();
    }
    if (tid < 16) logits[tid] = part[0][tid] + bg[tid];
    __syncthreads();
    if (tid == 0) {
        float v0 = -1e30f, v1 = -1e30f; int i0 = -1, i1 = -1;
        for (int e = 0; e < 16; e++) { float v = logits[e]; if (v > v0) { v0 = v; i0 = e; } }
        for (int e = 0; e < 16; e++) { if (e == i0) continue; float v = logits[e]; if (v > v1) { v1 = v; i1 = e; } }
        float ex = __expf(v1 - v0);
        float w0 = 1.f / (1.f + ex);
        float w1 = ex / (1.f + ex);
        int p0 = atomicAdd(&cnt[i0], 1);
        int p1 = atomicAdd(&cnt[i1], 1);
        tok_e[t * 2 + 0] = i0; tok_e[t * 2 + 1] = i1;
        tok_pos[t * 2 + 0] = p0; tok_pos[t * 2 + 1] = p1;
        tok_w[t * 2 + 0] = w0; tok_w[t * 2 + 1] = w1;
    }
}

// ---------------- scan: row bases + cumulative 256-row mtiles ---------------
__global__ void scan_kernel(const int* cnt, int* base, int* mb)
{
    if (threadIdx.x == 0 && blockIdx.x == 0) {
        int b = 0, m = 0;
        for (int e = 0; e < En; e++) {
            base[e] = b; mb[e] = m;
            b += cnt[e];
            m += (cnt[e] + 255) >> 8;
        }
        base[En] = b; mb[En] = m;
    }
}

// ---------------- gather ----------------------------------------------------
__global__ __launch_bounds__(256) void gather_kernel(
    const float* __restrict__ x, const int* tok_e, const int* tok_pos,
    const int* base, unsigned short* xg)
{
    int t = blockIdx.x; int tid = threadIdx.x;
    int e0 = tok_e[2 * t], e1 = tok_e[2 * t + 1];
    int r0 = base[e0] + tok_pos[2 * t];
    int r1 = base[e1] + tok_pos[2 * t + 1];
    float4 v = *reinterpret_cast<const float4*>(x + (size_t)t * Dn + tid * 4);
    ushort4 u;
    u.x = f2bf(v.x); u.y = f2bf(v.y); u.z = f2bf(v.z); u.w = f2bf(v.w);
    *reinterpret_cast<ushort4*>(xg + (size_t)r0 * Dn + tid * 4) = u;
    *reinterpret_cast<ushort4*>(xg + (size_t)r1 * Dn + tid * 4) = u;
}

// ---------------- convT: [R][C] f32 -> [C][R] bf16, 64x64 tiles -------------
__global__ __launch_bounds__(512) void convT_kernel(
    const float* __restrict__ src, unsigned short* __restrict__ dst, int R, int C)
{
    int e = blockIdx.z;
    const float* s = src + (size_t)e * R * C;
    unsigned short* d = dst + (size_t)e * R * C;
    __shared__ float tile[64][65];
    int r0 = blockIdx.y * 64, c0 = blockIdx.x * 64;
    int tr = threadIdx.x >> 4;           // 0..31
    int tc4 = (threadIdx.x & 15) * 4;    // 0..60
    float4 v0 = *reinterpret_cast<const float4*>(s + (size_t)(r0 + tr) * C + c0 + tc4);
    float4 v1 = *reinterpret_cast<const float4*>(s + (size_t)(r0 + tr + 32) * C + c0 + tc4);
    tile[tr][tc4 + 0] = v0.x; tile[tr][tc4 + 1] = v0.y;
    tile[tr][tc4 + 2] = v0.z; tile[tr][tc4 + 3] = v0.w;
    tile[tr + 32][tc4 + 0] = v1.x; tile[tr + 32][tc4 + 1] = v1.y;
    tile[tr + 32][tc4 + 2] = v1.z; tile[tr + 32][tc4 + 3] = v1.w;
    __syncthreads();
    ushort4 u0, u1;
    u0.x = f2bf(tile[tc4 + 0][tr]);      u1.x = f2bf(tile[tc4 + 0][tr + 32]);
    u0.y = f2bf(tile[tc4 + 1][tr]);      u1.y = f2bf(tile[tc4 + 1][tr + 32]);
    u0.z = f2bf(tile[tc4 + 2][tr]);      u1.z = f2bf(tile[tc4 + 2][tr + 32]);
    u0.w = f2bf(tile[tc4 + 3][tr]);      u1.w = f2bf(tile[tc4 + 3][tr + 32]);
    *reinterpret_cast<ushort4*>(d + (size_t)(c0 + tr) * R + r0 + tc4) = u0;
    *reinterpret_cast<ushort4*>(d + (size_t)(c0 + tr + 32) * R + r0 + tc4) = u1;
}

// ---------------- 8-phase GEMM core, XCD-locality decodes -------------------
// G1 (x @ W1t): KDIM=1024, NOUT=4096. bid -> xcd=bid&7, k=bid>>3,
//   gm=k>>1, ns=k&1, ntile=xcd*2+ns. XCD owns column pair -> B L2-resident.
// G2 (hg @ W2t): KDIM=4096 split in 2 K-halves. bid -> xcd=bid&7,
//   ncol=xcd>>1, kh=xcd&1, gm=bid>>3. Writes f32 partial to y[kh].
template<bool G1>
__global__ __launch_bounds__(512, 2) void gemm8p_kernel(
    const unsigned short* __restrict__ Ag, const unsigned short* __restrict__ Bg,
    const float* __restrict__ bias, unsigned short* __restrict__ outb,
    float* __restrict__ outf, size_t ystride,
    const int* __restrict__ cnt, const int* __restrict__ base,
    const int* __restrict__ mb)
{
    constexpr int KDIM = G1 ? Dn : Hn;     // row stride of A and B
    constexpr int KLEN = G1 ? Dn : (Hn / 2);
    constexpr int NOUT = G1 ? Hn : Dn;
    constexpr int NT = KLEN / 32;
    __shared__ unsigned short ldsA[4][256 * 32];
    __shared__ unsigned short ldsB[4][256 * 32];

    int bid = blockIdx.x;
    int xcd = bid & 7;
    int gm, ntile, kh;
    if constexpr (G1) {
        int k = bid >> 3;
        gm = k >> 1;
        ntile = xcd * 2 + (k & 1);
        kh = 0;
    } else {
        gm = bid >> 3;
        ntile = xcd >> 1;
        kh = xcd & 1;
    }
    if (gm >= mb[En]) return;            // block-uniform exit
    int e = find_e(mb, gm);
    int mtile = gm - mb[e];
    int M_e = cnt[e];
    int m0 = mtile * 256, n0 = ntile * 256;
    int kbase = kh * KLEN;
    int rowbase0 = base[e] + m0;
    const unsigned short* Ab = Ag + (size_t)rowbase0 * KDIM + kbase;
    const unsigned short* Bb = Bg + (size_t)e * NOUT * KDIM + (size_t)n0 * KDIM + kbase;

    int tid = threadIdx.x;
    int lane = tid & 63;
    int wid = tid >> 6;
    int wr = wid >> 2, wc = wid & 3;
    int lr16 = lane & 15, lk = lane >> 4;

    // staging source addrs (global pre-swizzled -> linear LDS dest ends up
    // XOR-swizzled; frag reads apply the same involution)
    int ja0 = tid;        int ra0 = ja0 >> 2; int ca0 = (ja0 & 3) ^ ((ra0 >> 1) & 3);
    int ja1 = tid + 512;  int ra1 = ja1 >> 2; int ca1 = (ja1 & 3) ^ ((ra1 >> 1) & 3);
    const unsigned short* aSrc0 = Ab + (size_t)ra0 * KDIM + ca0 * 8;
    const unsigned short* aSrc1 = Ab + (size_t)ra1 * KDIM + ca1 * 8;
    const unsigned short* bSrc0 = Bb + (size_t)ra0 * KDIM + ca0 * 8;
    const unsigned short* bSrc1 = Bb + (size_t)ra1 * KDIM + ca1 * 8;

    // fragment LDS offsets (elems, slot-relative), swizzled
    int aoff[8], boff[4];
#pragma unroll
    for (int m = 0; m < 8; m++) {
        int row = wr * 128 + m * 16 + lr16;
        aoff[m] = row * 32 + ((lk ^ ((row >> 1) & 3)) << 3);
    }
#pragma unroll
    for (int n = 0; n < 4; n++) {
        int row = wc * 64 + n * 16 + lr16;
        boff[n] = row * 32 + ((lk ^ ((row >> 1) & 3)) << 3);
    }

    f32x4 acc[8][4];
#pragma unroll
    for (int m = 0; m < 8; m++)
#pragma unroll
        for (int n = 0; n < 4; n++) acc[m][n] = (f32x4){0.f, 0.f, 0.f, 0.f};

    auto stageA = [&](int t) {
        char* sa = (char*)ldsA[t & 3];
        int k0 = t * 32;
        gload_lds16(aSrc0 + k0, sa + ja0 * 16);
        gload_lds16(aSrc1 + k0, sa + ja1 * 16);
    };
    auto stageB = [&](int t) {
        char* sb = (char*)ldsB[t & 3];
        int k0 = t * 32;
        gload_lds16(bSrc0 + k0, sb + ja0 * 16);
        gload_lds16(bSrc1 + k0, sb + ja1 * 16);
    };

    stageB(0); stageA(0);
    stageB(1); stageA(1);
    stageB(2); stageA(2);
    waitvm8();
    barrier_raw();

#pragma unroll 4
    for (int t = 0; t < NT; ++t) {
        const unsigned short* sa = ldsA[t & 3];
        const unsigned short* sb = ldsB[t & 3];
        bf16x8 a[4], b[4];
        // ---- phase 1: m-low ----
#pragma unroll
        for (int m = 0; m < 4; m++) a[m] = *(const bf16x8*)(sa + aoff[m]);
#pragma unroll
        for (int n = 0; n < 4; n++) b[n] = *(const bf16x8*)(sb + boff[n]);
        if (t + 3 < NT) stageB(t + 3);
        barrier_raw();
        waitlgkm0();
        __builtin_amdgcn_s_setprio(1);
#pragma unroll
        for (int m = 0; m < 4; m++)
#pragma unroll
            for (int n = 0; n < 4; n++)
                acc[m][n] = __builtin_amdgcn_mfma_f32_16x16x32_bf16(b[n], a[m], acc[m][n], 0, 0, 0);
        __builtin_amdgcn_s_setprio(0);
        barrier_raw();
        // ---- phase 2: m-high ----
#pragma unroll
        for (int m = 0; m < 4; m++) a[m] = *(const bf16x8*)(sa + aoff[m + 4]);
        if (t + 3 < NT) stageA(t + 3);
        barrier_raw();
        waitlgkm0();
        __builtin_amdgcn_s_setprio(1);
#pragma unroll
        for (int m = 0; m < 4; m++)
#pragma unroll
            for (int n = 0; n < 4; n++)
                acc[m + 4][n] = __builtin_amdgcn_mfma_f32_16x16x32_bf16(b[n], a[m], acc[m + 4][n], 0, 0, 0);
        __builtin_amdgcn_s_setprio(0);
        if (t < NT - 3)       waitvm8();
        else if (t == NT - 3) waitvm4();
        else if (t == NT - 2) waitvm0();
        barrier_raw();
    }

    // ---- epilogue: lane holds row (lr16) x 4 consecutive cols ----
    bool addb = G1 || (kh == 0);
    const float* be = bias + (size_t)e * NOUT;
    int lj = (lane >> 4) * 4;
    float* yb = outf + (G1 ? 0 : (size_t)kh * ystride);
#pragma unroll
    for (int m = 0; m < 8; m++) {
        int rt = wr * 128 + m * 16 + lr16;
        if (m0 + rt < M_e) {
            size_t rowoff = (size_t)(rowbase0 + rt) * NOUT;
#pragma unroll
            for (int n = 0; n < 4; n++) {
                int col0 = n0 + wc * 64 + n * 16 + lj;
                float4 bs = addb ? *reinterpret_cast<const float4*>(be + col0)
                                 : (float4){0.f, 0.f, 0.f, 0.f};
                float v0 = acc[m][n][0] + bs.x;
                float v1 = acc[m][n][1] + bs.y;
                float v2 = acc[m][n][2] + bs.z;
                float v3 = acc[m][n][3] + bs.w;
                if constexpr (G1) {
                    ushort4 u;
                    u.x = f2bf(fmaxf(v0, 0.f));
                    u.y = f2bf(fmaxf(v1, 0.f));
                    u.z = f2bf(fmaxf(v2, 0.f));
                    u.w = f2bf(fmaxf(v3, 0.f));
                    *reinterpret_cast<ushort4*>(outb + rowoff + col0) = u;
                } else {
                    float4 o = {v0, v1, v2, v3};
                    *reinterpret_cast<float4*>(yb + rowoff + col0) = o;
                }
            }
        }
    }
}

// ---------------- combine: out[t] = w0*(y0+y1)[r0] + w1*(y0+y1)[r1] ---------
__global__ __launch_bounds__(256) void combine_kernel(
    const float* __restrict__ y, size_t ystride,
    const int* __restrict__ tok_e, const int* __restrict__ tok_pos,
    const int* __restrict__ base, const float* __restrict__ tok_w,
    float* __restrict__ out)
{
    int t = blockIdx.x, tid = threadIdx.x;
    int e0 = tok_e[2 * t], e1 = tok_e[2 * t + 1];
    int r0 = base[e0] + tok_pos[2 * t];
    int r1 = base[e1] + tok_pos[2 * t + 1];
    float w0 = tok_w[2 * t], w1 = tok_w[2 * t + 1];
    const float* y1 = y + ystride;
    float4 a0 = *reinterpret_cast<const float4*>(y  + (size_t)r0 * Dn + tid * 4);
    float4 a1 = *reinterpret_cast<const float4*>(y1 + (size_t)r0 * Dn + tid * 4);
    float4 b0 = *reinterpret_cast<const float4*>(y  + (size_t)r1 * Dn + tid * 4);
    float4 b1 = *reinterpret_cast<const float4*>(y1 + (size_t)r1 * Dn + tid * 4);
    float4 o;
    o.x = w0 * (a0.x + a1.x) + w1 * (b0.x + b1.x);
    o.y = w0 * (a0.y + a1.y) + w1 * (b0.y + b1.y);
    o.z = w0 * (a0.z + a1.z) + w1 * (b0.z + b1.z);
    o.w = w0 * (a0.w + a1.w) + w1 * (b0.w + b1.w);
    *reinterpret_cast<float4*>(out + (size_t)t * Dn + tid * 4) = o;
}

// ---------------- launch ----------------------------------------------------
extern "C" void kernel_launch(void* const* d_in, const int* in_sizes, int n_in,
                              void* d_out, int out_size, void* d_ws, size_t ws_size,
                              hipStream_t stream)
{
    const float* x  = (const float*)d_in[0];
    const float* Wg = (const float*)d_in[1];
    const float* bg = (const float*)d_in[2];
    const float* W1 = (const float*)d_in[3];
    const float* b1 = (const float*)d_in[4];
    const float* W2 = (const float*)d_in[5];
    const float* b2 = (const float*)d_in[6];
    float* out = (float*)d_out;

    char* ws = (char*)d_ws;
    size_t off = 0;
    auto alloc = [&](size_t bytes) {
        size_t o = off; off += (bytes + 255) & ~(size_t)255; return o;
    };
    const int ROWS = Tn * 2;            // 16384 dispatch rows
    const int RCAP = ROWS + 256;        // slack for 256-row tile overreads
    const size_t YSTR = (size_t)RCAP * Dn;

    unsigned short* Wt = (unsigned short*)(ws + alloc((size_t)En * Hn * Dn * 2)); // W1t then W2t
    unsigned short* xg = (unsigned short*)(ws + alloc((size_t)RCAP * Dn * 2));
    unsigned short* hg = (unsigned short*)(ws + alloc((size_t)RCAP * Hn * 2));
    float* yv      = (float*)(ws + alloc(2 * YSTR * 4));        // y0 | y1
    int*   cnt     = (int*)(ws + alloc(En * 4));
    int*   base    = (int*)(ws + alloc((En + 1) * 4));
    int*   mb      = (int*)(ws + alloc((En + 1) * 4));
    int*   tok_e   = (int*)(ws + alloc(Tn * 2 * 4));
    int*   tok_pos = (int*)(ws + alloc(Tn * 2 * 4));
    float* tok_w   = (float*)(ws + alloc(Tn * 2 * 4));
    (void)ws_size; (void)in_sizes; (void)n_in; (void)out_size;

    hipMemsetAsync(cnt, 0, En * 4, stream);

    gate_kernel<<<Tn, 256, 0, stream>>>(x, Wg, bg, cnt, tok_e, tok_pos, tok_w);
    scan_kernel<<<1, 64, 0, stream>>>(cnt, base, mb);
    gather_kernel<<<Tn, 256, 0, stream>>>(x, tok_e, tok_pos, base, xg);

    // W1 [E][Dn][Hn] -> Wt [E][Hn][Dn] bf16
    convT_kernel<<<dim3(Hn / 64, Dn / 64, En), 512, 0, stream>>>(W1, Wt, Dn, Hn);
    // gemm1: worst total_m = 80; grid = 8 xcd * (80 gm * 2 ns)
    gemm8p_kernel<true><<<1280, 512, 0, stream>>>(
        xg, Wt, b1, hg, nullptr, 0, cnt, base, mb);

    // W2 [E][Hn][Dn] -> Wt [E][Dn][Hn] bf16
    convT_kernel<<<dim3(Dn / 64, Hn / 64, En), 512, 0, stream>>>(W2, Wt, Hn, Dn);
    // gemm2: K-split 2; grid = 8 xcd * 80 gm
    gemm8p_kernel<false><<<640, 512, 0, stream>>>(
        hg, Wt, b2, nullptr, yv, YSTR, cnt, base, mb);

    combine_kernel<<<Tn, 256, 0, stream>>>(yv, YSTR, tok_e, tok_pos, base, tok_w, out);
}

// Round 6
// 737.203 us; speedup vs baseline: 1.4998x; 1.1511x over previous
//
#include <hip/hip_runtime.h>
#include <hip/hip_bf16.h>
#include <stdint.h>

// MoE: T=8192, D=1024, H=4096, E=16, top-2. Sparse dispatch + bf16 MFMA GEMMs.
// 256x256 8-phase GEMM core (ring-4 BK=32, counted vmcnt, T2 swizzle).
// NEW: persistent 256-block GEMMs (1 block/CU) looping XCD/K-aligned rounds
// so same-panel blocks stay co-resident and sweep K together (L2 re-use);
// gate rewritten to 16-token blocks with LDS-transposed Wg (kills the
// 512 MB Wg re-read stream).

#define Tn 8192
#define Dn 1024
#define Hn 4096
#define En 16

typedef __attribute__((ext_vector_type(8))) short bf16x8;
typedef __attribute__((ext_vector_type(4))) float f32x4;

__device__ __forceinline__ unsigned short f2bf(float f) {
    union { __hip_bfloat16 h; unsigned short u; } cv;
    cv.h = __float2bfloat16(f);
    return cv.u;
}

__device__ __forceinline__ void gload_lds16(const void* gptr, void* lptr) {
    __builtin_amdgcn_global_load_lds(
        (const __attribute__((address_space(1))) uint32_t*)gptr,
        (__attribute__((address_space(3))) uint32_t*)lptr, 16, 0, 0);
}

// e = #{i in [1,En) : mb[i] <= gm}
__device__ __forceinline__ int find_e(const int* __restrict__ mb, int gm) {
    int e = 0;
#pragma unroll
    for (int i = 1; i < En; i++) e += (mb[i] <= gm) ? 1 : 0;
    return e;
}

__device__ __forceinline__ void waitvm8() { asm volatile("s_waitcnt vmcnt(8)" ::: "memory"); }
__device__ __forceinline__ void waitvm4() { asm volatile("s_waitcnt vmcnt(4)" ::: "memory"); }
__device__ __forceinline__ void waitvm0() { asm volatile("s_waitcnt vmcnt(0)" ::: "memory"); }
__device__ __forceinline__ void waitlgkm0() { asm volatile("s_waitcnt lgkmcnt(0)" ::: "memory"); }
__device__ __forceinline__ void barrier_raw() { asm volatile("s_barrier" ::: "memory"); }

__device__ __forceinline__ bool better(float va, int ia, float vb, int ib) {
    return (va > vb) || (va == vb && ia < ib);
}

// ---------------- gate: 16 tokens/block, Wg in LDS, shuffle top-2 -----------
__global__ __launch_bounds__(256) void gate_kernel(
    const float* __restrict__ x, const float* __restrict__ Wg,
    const float* __restrict__ bg,
    int* cnt, int* tok_e, int* tok_pos, float* tok_w)
{
    __shared__ float wgt[16 * 1028];   // wgt[e][k], stride 1028 (2-way banks = free)
    int tid = threadIdx.x;
    int t0 = blockIdx.x * 16;

    // transpose-load Wg [1024][16] f32 -> wgt[e][k]
#pragma unroll
    for (int i = 0; i < 64; i++) {
        int idx = i * 256 + tid;          // 0..16383, coalesced read
        int k = idx >> 4, e = idx & 15;
        wgt[e * 1028 + k] = Wg[idx];
    }
    __syncthreads();

    int tok = tid >> 4, e = tid & 15;     // 16 tokens x 16 experts
    const float4* xr = reinterpret_cast<const float4*>(x + (size_t)(t0 + tok) * Dn);
    const float4* wr = reinterpret_cast<const float4*>(&wgt[e * 1028]);
    float acc = 0.f;
#pragma unroll 8
    for (int q = 0; q < 256; q++) {
        float4 xv = xr[q], wv = wr[q];
        acc += xv.x * wv.x + xv.y * wv.y + xv.z * wv.z + xv.w * wv.w;
    }
    acc += bg[e];

    // 16-lane butterfly top-2 merge (value desc, index-asc tiebreak)
    float v0 = acc, v1 = -1e30f;
    int i0 = e, i1 = -1;
#pragma unroll
    for (int m = 1; m < 16; m <<= 1) {
        float ov0 = __shfl_xor(v0, m, 16); int oi0 = __shfl_xor(i0, m, 16);
        float ov1 = __shfl_xor(v1, m, 16); int oi1 = __shfl_xor(i1, m, 16);
        if (better(ov0, oi0, v0, i0)) {
            if (better(v0, i0, ov1, oi1)) { v1 = v0; i1 = i0; }
            else                          { v1 = ov1; i1 = oi1; }
            v0 = ov0; i0 = oi0;
        } else if (better(ov0, oi0, v1, i1)) {
            v1 = ov0; i1 = oi0;
        }
    }
    if (e == 0) {
        float ex = __expf(v1 - v0);
        float w0 = 1.f / (1.f + ex);
        float w1 = ex / (1.f + ex);
        int p0 = atomicAdd(&cnt[i0], 1);
        int p1 = atomicAdd(&cnt[i1], 1);
        int t = t0 + tok;
        tok_e[t * 2 + 0] = i0; tok_e[t * 2 + 1] = i1;
        tok_pos[t * 2 + 0] = p0; tok_pos[t * 2 + 1] = p1;
        tok_w[t * 2 + 0] = w0; tok_w[t * 2 + 1] = w1;
    }
}

// ---------------- scan: row bases + cumulative 256-row mtiles ---------------
__global__ void scan_kernel(const int* cnt, int* base, int* mb)
{
    if (threadIdx.x == 0 && blockIdx.x == 0) {
        int b = 0, m = 0;
        for (int e = 0; e < En; e++) {
            base[e] = b; mb[e] = m;
            b += cnt[e];
            m += (cnt[e] + 255) >> 8;
        }
        base[En] = b; mb[En] = m;
    }
}

// ---------------- gather ----------------------------------------------------
__global__ __launch_bounds__(256) void gather_kernel(
    const float* __restrict__ x, const int* tok_e, const int* tok_pos,
    const int* base, unsigned short* xg)
{
    int t = blockIdx.x; int tid = threadIdx.x;
    int e0 = tok_e[2 * t], e1 = tok_e[2 * t + 1];
    int r0 = base[e0] + tok_pos[2 * t];
    int r1 = base[e1] + tok_pos[2 * t + 1];
    float4 v = *reinterpret_cast<const float4*>(x + (size_t)t * Dn + tid * 4);
    ushort4 u;
    u.x = f2bf(v.x); u.y = f2bf(v.y); u.z = f2bf(v.z); u.w = f2bf(v.w);
    *reinterpret_cast<ushort4*>(xg + (size_t)r0 * Dn + tid * 4) = u;
    *reinterpret_cast<ushort4*>(xg + (size_t)r1 * Dn + tid * 4) = u;
}

// ---------------- convT: [R][C] f32 -> [C][R] bf16, 64x64 tiles -------------
__global__ __launch_bounds__(512) void convT_kernel(
    const float* __restrict__ src, unsigned short* __restrict__ dst, int R, int C)
{
    int e = blockIdx.z;
    const float* s = src + (size_t)e * R * C;
    unsigned short* d = dst + (size_t)e * R * C;
    __shared__ float tile[64][65];
    int r0 = blockIdx.y * 64, c0 = blockIdx.x * 64;
    int tr = threadIdx.x >> 4;           // 0..31
    int tc4 = (threadIdx.x & 15) * 4;    // 0..60
    float4 v0 = *reinterpret_cast<const float4*>(s + (size_t)(r0 + tr) * C + c0 + tc4);
    float4 v1 = *reinterpret_cast<const float4*>(s + (size_t)(r0 + tr + 32) * C + c0 + tc4);
    tile[tr][tc4 + 0] = v0.x; tile[tr][tc4 + 1] = v0.y;
    tile[tr][tc4 + 2] = v0.z; tile[tr][tc4 + 3] = v0.w;
    tile[tr + 32][tc4 + 0] = v1.x; tile[tr + 32][tc4 + 1] = v1.y;
    tile[tr + 32][tc4 + 2] = v1.z; tile[tr + 32][tc4 + 3] = v1.w;
    __syncthreads();
    ushort4 u0, u1;
    u0.x = f2bf(tile[tc4 + 0][tr]);      u1.x = f2bf(tile[tc4 + 0][tr + 32]);
    u0.y = f2bf(tile[tc4 + 1][tr]);      u1.y = f2bf(tile[tc4 + 1][tr + 32]);
    u0.z = f2bf(tile[tc4 + 2][tr]);      u1.z = f2bf(tile[tc4 + 2][tr + 32]);
    u0.w = f2bf(tile[tc4 + 3][tr]);      u1.w = f2bf(tile[tc4 + 3][tr + 32]);
    *reinterpret_cast<ushort4*>(d + (size_t)(c0 + tr) * R + r0 + tc4) = u0;
    *reinterpret_cast<ushort4*>(d + (size_t)(c0 + tr + 32) * R + r0 + tc4) = u1;
}

// ---------------- persistent 8-phase GEMM, XCD/K-aligned rounds -------------
// Grid = 256 blocks exactly (1/CU, 128 KiB LDS). Block loops rounds; per round:
// G1: 16 gm x 16 nt  (xcd owns nt pair {2x,2x+1}; slot>>1 = gm offset)
// G2: 32 gm x (nt = xcd>>1, kh = xcd&1), K split in 2 halves of 2048.
// Same-B blocks (mtiles of one expert) are co-resident on one XCD and sweep
// K together -> B-subtile re-reads are L2 hits.
template<bool G1>
__global__ __launch_bounds__(512, 2) void gemm8p_kernel(
    const unsigned short* __restrict__ Ag, const unsigned short* __restrict__ Bg,
    const float* __restrict__ bias, unsigned short* __restrict__ outb,
    float* __restrict__ outf, size_t ystride,
    const int* __restrict__ cnt, const int* __restrict__ base,
    const int* __restrict__ mb)
{
    constexpr int KDIM = G1 ? Dn : Hn;     // row stride of A and B
    constexpr int KLEN = G1 ? Dn : (Hn / 2);
    constexpr int NOUT = G1 ? Hn : Dn;
    constexpr int NT = KLEN / 32;
    __shared__ unsigned short ldsA[4][256 * 32];
    __shared__ unsigned short ldsB[4][256 * 32];

    int bid = blockIdx.x;
    int xcd = bid & 7;
    int slot = bid >> 3;                  // 0..31
    int totalgm = mb[En];
    int rounds = G1 ? ((totalgm + 15) >> 4) : ((totalgm + 31) >> 5);

    int tid = threadIdx.x;
    int lane = tid & 63;
    int wid = tid >> 6;
    int wr = wid >> 2, wc = wid & 3;
    int lr16 = lane & 15, lk = lane >> 4;
    int lj = (lane >> 4) * 4;

    // staging source decomposition (global pre-swizzled -> linear LDS dest
    // ends up XOR-swizzled; frag reads apply the same involution)
    int ja0 = tid;        int ra0 = ja0 >> 2; int ca0 = (ja0 & 3) ^ ((ra0 >> 1) & 3);
    int ja1 = tid + 512;  int ra1 = ja1 >> 2; int ca1 = (ja1 & 3) ^ ((ra1 >> 1) & 3);

    // fragment LDS offsets (elems, slot-relative), swizzled
    int aoff[8], boff[4];
#pragma unroll
    for (int m = 0; m < 8; m++) {
        int row = wr * 128 + m * 16 + lr16;
        aoff[m] = row * 32 + ((lk ^ ((row >> 1) & 3)) << 3);
    }
#pragma unroll
    for (int n = 0; n < 4; n++) {
        int row = wc * 64 + n * 16 + lr16;
        boff[n] = row * 32 + ((lk ^ ((row >> 1) & 3)) << 3);
    }

    for (int r = 0; r < rounds; r++) {
        int gm, ntile, kh;
        if constexpr (G1) {
            gm = r * 16 + (slot >> 1);
            ntile = xcd * 2 + (slot & 1);
            kh = 0;
        } else {
            gm = r * 32 + slot;
            ntile = xcd >> 1;
            kh = xcd & 1;
        }
        if (gm >= totalgm) continue;

        int e = find_e(mb, gm);
        int mtile = gm - mb[e];
        int M_e = cnt[e];
        int m0 = mtile * 256, n0 = ntile * 256;
        int kbase = kh * KLEN;
        int rowbase0 = base[e] + m0;
        const unsigned short* Ab = Ag + (size_t)rowbase0 * KDIM + kbase;
        const unsigned short* Bb = Bg + (size_t)e * NOUT * KDIM + (size_t)n0 * KDIM + kbase;

        const unsigned short* aSrc0 = Ab + (size_t)ra0 * KDIM + ca0 * 8;
        const unsigned short* aSrc1 = Ab + (size_t)ra1 * KDIM + ca1 * 8;
        const unsigned short* bSrc0 = Bb + (size_t)ra0 * KDIM + ca0 * 8;
        const unsigned short* bSrc1 = Bb + (size_t)ra1 * KDIM + ca1 * 8;

        f32x4 acc[8][4];
#pragma unroll
        for (int m = 0; m < 8; m++)
#pragma unroll
            for (int n = 0; n < 4; n++) acc[m][n] = (f32x4){0.f, 0.f, 0.f, 0.f};

        auto stageA = [&](int t) {
            char* sa = (char*)ldsA[t & 3];
            int k0 = t * 32;
            gload_lds16(aSrc0 + k0, sa + ja0 * 16);
            gload_lds16(aSrc1 + k0, sa + ja1 * 16);
        };
        auto stageB = [&](int t) {
            char* sb = (char*)ldsB[t & 3];
            int k0 = t * 32;
            gload_lds16(bSrc0 + k0, sb + ja0 * 16);
            gload_lds16(bSrc1 + k0, sb + ja1 * 16);
        };

        stageB(0); stageA(0);
        stageB(1); stageA(1);
        stageB(2); stageA(2);
        waitvm8();               // drains pending epilogue stores + sub-tile 0
        barrier_raw();

#pragma unroll 4
        for (int t = 0; t < NT; ++t) {
            const unsigned short* sa = ldsA[t & 3];
            const unsigned short* sb = ldsB[t & 3];
            bf16x8 a[4], b[4];
            // ---- phase 1: m-low ----
#pragma unroll
            for (int m = 0; m < 4; m++) a[m] = *(const bf16x8*)(sa + aoff[m]);
#pragma unroll
            for (int n = 0; n < 4; n++) b[n] = *(const bf16x8*)(sb + boff[n]);
            if (t + 3 < NT) stageB(t + 3);
            barrier_raw();
            waitlgkm0();
            __builtin_amdgcn_s_setprio(1);
#pragma unroll
            for (int m = 0; m < 4; m++)
#pragma unroll
                for (int n = 0; n < 4; n++)
                    acc[m][n] = __builtin_amdgcn_mfma_f32_16x16x32_bf16(b[n], a[m], acc[m][n], 0, 0, 0);
            __builtin_amdgcn_s_setprio(0);
            barrier_raw();
            // ---- phase 2: m-high ----
#pragma unroll
            for (int m = 0; m < 4; m++) a[m] = *(const bf16x8*)(sa + aoff[m + 4]);
            if (t + 3 < NT) stageA(t + 3);
            barrier_raw();
            waitlgkm0();
            __builtin_amdgcn_s_setprio(1);
#pragma unroll
            for (int m = 0; m < 4; m++)
#pragma unroll
                for (int n = 0; n < 4; n++)
                    acc[m + 4][n] = __builtin_amdgcn_mfma_f32_16x16x32_bf16(b[n], a[m], acc[m + 4][n], 0, 0, 0);
            __builtin_amdgcn_s_setprio(0);
            if (t < NT - 3)       waitvm8();
            else if (t == NT - 3) waitvm4();
            else if (t == NT - 2) waitvm0();
            barrier_raw();
        }

        // ---- epilogue: lane holds row (lr16) x 4 consecutive cols ----
        bool addb = G1 || (kh == 0);
        const float* be = bias + (size_t)e * NOUT;
        float* yb = outf + (G1 ? 0 : (size_t)kh * ystride);
#pragma unroll
        for (int m = 0; m < 8; m++) {
            int rt = wr * 128 + m * 16 + lr16;
            if (m0 + rt < M_e) {
                size_t rowoff = (size_t)(rowbase0 + rt) * NOUT;
#pragma unroll
                for (int n = 0; n < 4; n++) {
                    int col0 = n0 + wc * 64 + n * 16 + lj;
                    float4 bs = addb ? *reinterpret_cast<const float4*>(be + col0)
                                     : (float4){0.f, 0.f, 0.f, 0.f};
                    float v0 = acc[m][n][0] + bs.x;
                    float v1 = acc[m][n][1] + bs.y;
                    float v2 = acc[m][n][2] + bs.z;
                    float v3 = acc[m][n][3] + bs.w;
                    if constexpr (G1) {
                        ushort4 u;
                        u.x = f2bf(fmaxf(v0, 0.f));
                        u.y = f2bf(fmaxf(v1, 0.f));
                        u.z = f2bf(fmaxf(v2, 0.f));
                        u.w = f2bf(fmaxf(v3, 0.f));
                        *reinterpret_cast<ushort4*>(outb + rowoff + col0) = u;
                    } else {
                        float4 o = {v0, v1, v2, v3};
                        *reinterpret_cast<float4*>(yb + rowoff + col0) = o;
                    }
                }
            }
        }
    }
}

// ---------------- combine: out[t] = w0*(y0+y1)[r0] + w1*(y0+y1)[r1] ---------
__global__ __launch_bounds__(256) void combine_kernel(
    const float* __restrict__ y, size_t ystride,
    const int* __restrict__ tok_e, const int* __restrict__ tok_pos,
    const int* __restrict__ base, const float* __restrict__ tok_w,
    float* __restrict__ out)
{
    int t = blockIdx.x, tid = threadIdx.x;
    int e0 = tok_e[2 * t], e1 = tok_e[2 * t + 1];
    int r0 = base[e0] + tok_pos[2 * t];
    int r1 = base[e1] + tok_pos[2 * t + 1];
    float w0 = tok_w[2 * t], w1 = tok_w[2 * t + 1];
    const float* y1 = y + ystride;
    float4 a0 = *reinterpret_cast<const float4*>(y  + (size_t)r0 * Dn + tid * 4);
    float4 a1 = *reinterpret_cast<const float4*>(y1 + (size_t)r0 * Dn + tid * 4);
    float4 b0 = *reinterpret_cast<const float4*>(y  + (size_t)r1 * Dn + tid * 4);
    float4 b1 = *reinterpret_cast<const float4*>(y1 + (size_t)r1 * Dn + tid * 4);
    float4 o;
    o.x = w0 * (a0.x + a1.x) + w1 * (b0.x + b1.x);
    o.y = w0 * (a0.y + a1.y) + w1 * (b0.y + b1.y);
    o.z = w0 * (a0.z + a1.z) + w1 * (b0.z + b1.z);
    o.w = w0 * (a0.w + a1.w) + w1 * (b0.w + b1.w);
    *reinterpret_cast<float4*>(out + (size_t)t * Dn + tid * 4) = o;
}

// ---------------- launch ----------------------------------------------------
extern "C" void kernel_launch(void* const* d_in, const int* in_sizes, int n_in,
                              void* d_out, int out_size, void* d_ws, size_t ws_size,
                              hipStream_t stream)
{
    const float* x  = (const float*)d_in[0];
    const float* Wg = (const float*)d_in[1];
    const float* bg = (const float*)d_in[2];
    const float* W1 = (const float*)d_in[3];
    const float* b1 = (const float*)d_in[4];
    const float* W2 = (const float*)d_in[5];
    const float* b2 = (const float*)d_in[6];
    float* out = (float*)d_out;

    char* ws = (char*)d_ws;
    size_t off = 0;
    auto alloc = [&](size_t bytes) {
        size_t o = off; off += (bytes + 255) & ~(size_t)255; return o;
    };
    const int ROWS = Tn * 2;            // 16384 dispatch rows
    const int RCAP = ROWS + 256;        // slack for 256-row tile overreads
    const size_t YSTR = (size_t)RCAP * Dn;

    unsigned short* Wt = (unsigned short*)(ws + alloc((size_t)En * Hn * Dn * 2)); // W1t then W2t
    unsigned short* xg = (unsigned short*)(ws + alloc((size_t)RCAP * Dn * 2));
    unsigned short* hg = (unsigned short*)(ws + alloc((size_t)RCAP * Hn * 2));
    float* yv      = (float*)(ws + alloc(2 * YSTR * 4));        // y0 | y1
    int*   cnt     = (int*)(ws + alloc(En * 4));
    int*   base    = (int*)(ws + alloc((En + 1) * 4));
    int*   mb      = (int*)(ws + alloc((En + 1) * 4));
    int*   tok_e   = (int*)(ws + alloc(Tn * 2 * 4));
    int*   tok_pos = (int*)(ws + alloc(Tn * 2 * 4));
    float* tok_w   = (float*)(ws + alloc(Tn * 2 * 4));
    (void)ws_size; (void)in_sizes; (void)n_in; (void)out_size;

    hipMemsetAsync(cnt, 0, En * 4, stream);

    gate_kernel<<<Tn / 16, 256, 0, stream>>>(x, Wg, bg, cnt, tok_e, tok_pos, tok_w);
    scan_kernel<<<1, 64, 0, stream>>>(cnt, base, mb);
    gather_kernel<<<Tn, 256, 0, stream>>>(x, tok_e, tok_pos, base, xg);

    // W1 [E][Dn][Hn] -> Wt [E][Hn][Dn] bf16
    convT_kernel<<<dim3(Hn / 64, Dn / 64, En), 512, 0, stream>>>(W1, Wt, Dn, Hn);
    // gemm1: persistent 256 blocks, rounds of 16 gm x 16 nt
    gemm8p_kernel<true><<<256, 512, 0, stream>>>(
        xg, Wt, b1, hg, nullptr, 0, cnt, base, mb);

    // W2 [E][Hn][Dn] -> Wt [E][Dn][Hn] bf16
    convT_kernel<<<dim3(Dn / 64, Hn / 64, En), 512, 0, stream>>>(W2, Wt, Hn, Dn);
    // gemm2: persistent 256 blocks, rounds of 32 gm x (4 nt x 2 kh)
    gemm8p_kernel<false><<<256, 512, 0, stream>>>(
        hg, Wt, b2, nullptr, yv, YSTR, cnt, base, mb);

    combine_kernel<<<Tn, 256, 0, stream>>>(yv, YSTR, tok_e, tok_pos, base, tok_w, out);
}